// Round 7
// baseline (507.619 us; speedup 1.0000x reference)
//
#include <hip/hip_runtime.h>
#include <hip/hip_bf16.h>

// GCN attention forward, MI355X. fp32 inputs (counter-proven R14).
// Split: S~=78us; k0~2, k1~22 (adj HBM floor), k2~31, k3~25.
// k2/k3 falsified theories: request-rate (R22 null), bytes (R18 null),
// pipelining (R20 +4.5), nt-store L2 bypass (R24 +10.5 REGRESSED).
// R25 DIAGNOSTIC: exact R22 code (274.7us best) but k2/k3 bodies wrapped
// in x4 in-kernel rep loops (idempotent; syncthreads at rep boundaries)
// so each dispatch (~125/~100us) lands in rocprof top-5 and we finally
// read VALUBusy/FETCH/OccupancyPercent/VGPR/LDS-conflicts for them.
// k0 Wprep(+WkT) | k1 extract+fc(fp8) | k2 spmm+qk+h x4 | k3 attn x4.

#define NN    4096
#define ROWS  8192
#define OFT   256
#define CAP   128
#define NBLK  512
#define RPB   16
#define QLS   264   // qn_l row stride (ushort) — bank-spread for h-GEMM reads
#define K2REP 4
#define K3REP 4
#define EPSN  1e-12f
#define MFMA(a,b,c) __builtin_amdgcn_mfma_f32_16x16x32_bf16((a),(b),(c),0,0,0)

typedef unsigned short ushort_t;
typedef unsigned char  u8;
typedef __attribute__((ext_vector_type(8))) short bf16x8;
typedef __attribute__((ext_vector_type(4))) float f32x4;
typedef __attribute__((ext_vector_type(2))) float f32x2;

#define WP_FC   0
#define WP_Q    (16384 * 8)
#define WP_K    (WP_Q + 8192 * 8)
#define WP_V1   (WP_K + 8192 * 8)
#define WP_V2   (WP_V1 + 8192 * 8)
#define WP_KT   (WP_V2 + 8192 * 8)   // Wk transposed frags: [p-kmajor][o-col]

__device__ __forceinline__ float lo_f(unsigned u) { union { unsigned i; float f; } c; c.i = u << 16;          return c.f; }
__device__ __forceinline__ float hi_f(unsigned u) { union { unsigned i; float f; } c; c.i = u & 0xFFFF0000u;  return c.f; }
__device__ __forceinline__ float bf2f(ushort_t u) { union { unsigned i; float f; } c; c.i = (unsigned)u << 16; return c.f; }
__device__ __forceinline__ ushort_t f2bf(float f) {
    union { float f; unsigned i; } c; c.f = f;
    unsigned r = c.i + 0x7FFFu + ((c.i >> 16) & 1u);
    return (ushort_t)(r >> 16);
}
__device__ __forceinline__ unsigned pack2(float a, float b) {
    return (unsigned)f2bf(a) | ((unsigned)f2bf(b) << 16);
}

template<int CTRL>
__device__ __forceinline__ float dpp_add(float x) {
    union { float f; int i; } c; c.f = x;
    int y = __builtin_amdgcn_update_dpp(c.i, c.i, CTRL, 0xF, 0xF, false);
    union { int i; float f; } r; r.i = y;
    return x + r.f;
}

// ===================== k0: weight prep -> bf16 frag layout ==================
__global__ __launch_bounds__(256) void k0_prep(
    const float* __restrict__ Wfc, const float* __restrict__ Wq,
    const float* __restrict__ Wk,  const float* __restrict__ Wv1,
    const float* __restrict__ Wv2, ushort_t* __restrict__ Wp)
{
    int sid = blockIdx.x * 256 + threadIdx.x;
    if (sid >= 49152) {            // WkT: frag (p8, col=o): Wk[p8*8+i][o]
        int t = sid - 49152;       // 0..8191
        int o = t & 255, p8 = t >> 8;
        ushort_t tmp[8];
#pragma unroll
        for (int i = 0; i < 8; ++i)
            tmp[i] = f2bf(Wk[(size_t)(p8 * 8 + i) * 256 + o]);
        *(bf16x8*)(Wp + WP_KT + (size_t)t * 8) = *(bf16x8*)tmp;
        return;
    }
    const float* src; int K, local; ushort_t* dst;
    if (sid < 16384) { src = Wfc; K = 512; local = sid; dst = Wp + WP_FC + (size_t)local * 8; }
    else {
        int s = sid - 16384, which = s >> 13; local = s & 8191;
        const float* ws4[4] = {Wq, Wk, Wv1, Wv2};
        src = ws4[which]; K = 256;
        dst = Wp + WP_Q + (size_t)which * 65536 + (size_t)local * 8;
    }
    int col = local & 255, k8c = local >> 8;
    const float* p = src + (size_t)col * K + k8c * 8;
    float4 x0 = *(const float4*)p, x1 = *(const float4*)(p + 4);
    uint4 o; o.x = pack2(x0.x, x0.y); o.y = pack2(x0.z, x0.w);
    o.z = pack2(x1.x, x1.y); o.w = pack2(x1.z, x1.w);
    *(uint4*)dst = o;
}

// ============================ k1: extract + fc ==============================
__global__ __launch_bounds__(1024, 4) void k1_extract_fc(
    const float* __restrict__ seq, const float* __restrict__ adj,
    const ushort_t* __restrict__ Wp, u8* __restrict__ regA8,
    unsigned* __restrict__ gcols, int* __restrict__ cnt)
{
    __shared__ ushort_t Astage[64 * 17 * 8];
    __shared__ ushort_t csr_c[RPB * CAP];
    __shared__ int      csr_n[RPB];

    const int tid = threadIdx.x, wave = tid >> 6, lane = tid & 63;
    const int t16 = lane & 15, kq = lane >> 4;
    const int b = blockIdx.x, r0 = b * RPB;

    {   // extract: wave -> row; all 16 float4 loads up-front
        const float4* rowp = (const float4*)(adj + (size_t)(r0 + wave) * NN);
        float4 v[16];
#pragma unroll
        for (int t = 0; t < 16; ++t) v[t] = rowp[t * 64 + lane];
        int base = 0;
#pragma unroll
        for (int h = 0; h < 2; ++h) {
            int c = 0;
#pragma unroll
            for (int t = 0; t < 8; ++t) {
                const float4& x = v[h * 8 + t];
                c += (x.x > 0.f) + (x.y > 0.f) + (x.z > 0.f) + (x.w > 0.f);
            }
            int incl = c;
#pragma unroll
            for (int off = 1; off < 64; off <<= 1) {
                int y = __shfl_up(incl, off, 64);
                if (lane >= off) incl += y;
            }
            int p = base + incl - c;
            base += __shfl(incl, 63, 64);
#pragma unroll
            for (int t = 0; t < 8; ++t) {
                const float4& x = v[h * 8 + t];
                float f[4] = {x.x, x.y, x.z, x.w};
#pragma unroll
                for (int j = 0; j < 4; ++j)
                    if (f[j] > 0.f) {
                        if (p < CAP)
                            csr_c[wave * CAP + p] = (ushort_t)(((h * 8 + t) * 64 + lane) * 4 + j);
                        ++p;
                    }
            }
        }
        if (lane == 0) csr_n[wave] = (base < CAP) ? base : CAP;
    }
    __syncthreads();
    {
        const unsigned* cc = (const unsigned*)csr_c;
        if (tid < RPB * CAP / 2) gcols[b * (RPB * CAP / 2) + tid] = cc[tid];
        if (tid < RPB) cnt[r0 + tid] = csr_n[tid];
    }

    // ---- stage seq 16 x 512 (fp32 -> bf16, k-major frag layout)
    {
        int row = tid >> 6, seg = tid & 63;
        const float* p = seq + (size_t)(r0 + row) * 512 + seg * 8;
        float4 x0 = *(const float4*)p, x1 = *(const float4*)(p + 4);
        uint4 a;
        a.x = pack2(x0.x, x0.y); a.y = pack2(x0.z, x0.w);
        a.z = pack2(x1.x, x1.y); a.w = pack2(x1.z, x1.w);
        *(bf16x8*)(Astage + ((size_t)seg * 17 + row) * 8) = *(bf16x8*)&a;
    }
    __syncthreads();

    // ---- fc GEMM: wave -> 16 cols; epilogue -> fp8 x16 byte stores
    {
        const int col = wave * 16 + t16;
        const ushort_t* Wm = Wp + WP_FC;
        f32x4 a0 = {0.f, 0.f, 0.f, 0.f};
        for (int bch = 0; bch < 4; ++bch) {
            bf16x8 wb[4];
#pragma unroll
            for (int c2 = 0; c2 < 4; ++c2) {
                int k8c = (bch * 4 + c2) * 4 + kq;
                wb[c2] = *(const bf16x8*)(Wm + ((size_t)k8c * 256 + col) * 8);
            }
#pragma unroll
            for (int c2 = 0; c2 < 4; ++c2) {
                int c = bch * 4 + c2;
                bf16x8 af = *(const bf16x8*)(Astage + ((size_t)(c * 4 + kq) * 17 + t16) * 8);
                a0 = MFMA(af, wb[c2], a0);
            }
        }
#pragma unroll
        for (int r = 0; r < 4; ++r) {
            int t8 = __builtin_amdgcn_cvt_pk_fp8_f32(a0[r] * 16.f, 0.f, 0, false);
            regA8[(size_t)(r0 + kq * 4 + r) * OFT + col] = (u8)(t8 & 0xFF);
        }
    }
}

// ============== k2: spmm + q/k GEMM + norm + loss + h-GEMM (x K2REP) ========
__global__ __launch_bounds__(1024, 4) void k2_spmm_qk(
    const u8* __restrict__ regA8, unsigned* __restrict__ KO8,
    ushort_t* __restrict__ regH, const ushort_t* __restrict__ Wp,
    const unsigned* __restrict__ gcols, const int* __restrict__ cnt,
    float* __restrict__ part, float* __restrict__ invnk_g)
{
    __shared__ ushort_t Astage[32 * 17 * 8];
    __shared__ ushort_t csr_c[RPB * CAP];
    __shared__ ushort_t qn_l[RPB * QLS];
    __shared__ float    red[2][RPB][8];
    __shared__ float    dlred[16];

    const int tid = threadIdx.x, wave = tid >> 6, lane = tid & 63;
    const int t16 = lane & 15, kq = lane >> 4, grp = lane >> 4;
    const int b = blockIdx.x, r0 = b * RPB;
    const size_t batb = (size_t)(b >> 8) * 4096;

    {
        unsigned* cc = (unsigned*)csr_c;
        if (tid < RPB * CAP / 2) cc[tid] = gcols[b * (RPB * CAP / 2) + tid];
    }
    __syncthreads();

    for (int rep = 0; rep < K2REP; ++rep) {   // R25 diagnostic repetition

    // ---- spmm: wave -> row r0+wave
    {
        const int rl = wave;
        const int n = cnt[r0 + rl];
        const u8* gA = regA8 + batb * OFT;
        float a16[16];
#pragma unroll
        for (int j = 0; j < 16; ++j) a16[j] = 0.f;
        const int nIter = (n + 3) >> 2;
        uint4 v;
        {
            int e0 = grp; int val0 = (e0 < n);
            int col0 = csr_c[rl * CAP + (val0 ? e0 : 0)];
            v = *(const uint4*)(gA + (size_t)col0 * OFT + t16 * 16);
        }
        for (int it = 0; it < nIter; ++it) {
            uint4 vn;
            if (it + 1 < nIter) {
                int e1 = (it + 1) * 4 + grp; int val1 = (e1 < n);
                int col1 = csr_c[rl * CAP + (val1 ? e1 : 0)];
                vn = *(const uint4*)(gA + (size_t)col1 * OFT + t16 * 16);
            }
            int e = it * 4 + grp;
            if (e < n) {
                unsigned w4[4] = {v.x, v.y, v.z, v.w};
#pragma unroll
                for (int i2 = 0; i2 < 4; ++i2) {
                    f32x2 x01 = __builtin_amdgcn_cvt_pk_f32_fp8((int)w4[i2], false);
                    f32x2 x23 = __builtin_amdgcn_cvt_pk_f32_fp8((int)w4[i2], true);
                    a16[4*i2+0] += x01.x; a16[4*i2+1] += x01.y;
                    a16[4*i2+2] += x23.x; a16[4*i2+3] += x23.y;
                }
            }
            v = vn;
        }
#pragma unroll
        for (int j = 0; j < 16; ++j) {
            a16[j] += __shfl_xor(a16[j], 16, 64);
            a16[j] += __shfl_xor(a16[j], 32, 64);
        }
        float iv = 1.f / (16.f * (float)max(n, 1));
        float o0 = a16[grp*4+0]*iv, o1 = a16[grp*4+1]*iv;
        float o2 = a16[grp*4+2]*iv, o3 = a16[grp*4+3]*iv;
        int uo = 0;
        uo = __builtin_amdgcn_cvt_pk_fp8_f32(o0*16.f, o1*16.f, uo, false);
        uo = __builtin_amdgcn_cvt_pk_fp8_f32(o2*16.f, o3*16.f, uo, true);
        KO8[(size_t)(r0 + rl) * 64 + (t16 * 4 + grp)] = (unsigned)uo;
        int d0 = t16 * 16 + grp * 4;
        int q8c = d0 >> 3, off = d0 & 7;
        uint2 st; st.x = pack2(o0, o1); st.y = pack2(o2, o3);
        *(uint2*)(Astage + ((size_t)q8c * 17 + rl) * 8 + off) = st;
    }
    __syncthreads();

    // ---- q/k GEMM: waves 0-7 q, 8-15 k; wave -> 32 cols
    {
    const int isK = wave >> 3, w8 = wave & 7;
    const ushort_t* Wm = Wp + (isK ? WP_K : WP_Q);
    f32x4 acc[2];
    acc[0] = (f32x4){0.f,0.f,0.f,0.f};
    acc[1] = (f32x4){0.f,0.f,0.f,0.f};
    for (int bch = 0; bch < 2; ++bch) {
        bf16x8 wb[2][4];
#pragma unroll
        for (int j = 0; j < 2; ++j)
#pragma unroll
            for (int c2 = 0; c2 < 4; ++c2) {
                int col = w8 * 32 + j * 16 + t16;
                int k8c = (bch * 4 + c2) * 4 + kq;
                wb[j][c2] = *(const bf16x8*)(Wm + ((size_t)k8c * 256 + col) * 8);
            }
#pragma unroll
        for (int c2 = 0; c2 < 4; ++c2) {
            int c = bch * 4 + c2;
            bf16x8 af = *(const bf16x8*)(Astage + ((size_t)(c*4 + kq) * 17 + t16) * 8);
            acc[0] = MFMA(af, wb[0][c2], acc[0]);
            acc[1] = MFMA(af, wb[1][c2], acc[1]);
        }
    }
#pragma unroll
    for (int r = 0; r < 4; ++r) {
        float s = acc[0][r]*acc[0][r] + acc[1][r]*acc[1][r];
#pragma unroll
        for (int off = 1; off < 16; off <<= 1) s += __shfl_xor(s, off, 16);
        if (t16 == 0) red[isK][kq*4 + r][w8] = s;
    }
    __syncthreads();
#pragma unroll
    for (int r = 0; r < 4; ++r) {
        int row = kq * 4 + r;
        float s = 0.f;
#pragma unroll
        for (int j = 0; j < 8; ++j) s += red[isK][row][j];
        float inv = 1.f / fmaxf(sqrtf(s), EPSN);
        if (isK && w8 == 0 && t16 == 0) invnk_g[r0 + row] = inv;
#pragma unroll
        for (int j = 0; j < 2; ++j) {
            int col = w8 * 32 + j * 16 + t16;
            float v = acc[j][r] * inv;
            acc[j][r] = v;
            if (!isK) qn_l[row * QLS + col] = f2bf(v);
        }
    }
    __syncthreads();
    if (isK) {
        float dl = 0.f;
#pragma unroll
        for (int r = 0; r < 4; ++r) {
            int row = kq * 4 + r;
#pragma unroll
            for (int j = 0; j < 2; ++j) {
                int col = w8 * 32 + j * 16 + t16;
                float d = bf2f(qn_l[row * QLS + col]) - acc[j][r];
                dl += d * d;
            }
        }
#pragma unroll
        for (int off = 1; off < 64; off <<= 1) dl += __shfl_xor(dl, off, 64);
        if (lane == 0) dlred[wave] = dl;
    }
    }
    __syncthreads();

    // ---- h-GEMM: h[m] = qn[m] . Wk via WP_KT; 16 waves x 16 cols
    {
        const ushort_t* WmT = Wp + WP_KT;
        const int colh = wave * 16 + t16;
        f32x4 h0 = {0.f, 0.f, 0.f, 0.f};
        for (int bch = 0; bch < 2; ++bch) {
            bf16x8 wb[4];
#pragma unroll
            for (int c2 = 0; c2 < 4; ++c2) {
                int k8c = (bch * 4 + c2) * 4 + kq;
                wb[c2] = *(const bf16x8*)(WmT + ((size_t)k8c * 256 + colh) * 8);
            }
#pragma unroll
            for (int c2 = 0; c2 < 4; ++c2) {
                int k8c = (bch * 4 + c2) * 4 + kq;
                bf16x8 af = *(const bf16x8*)(qn_l + (size_t)t16 * QLS + k8c * 8);
                h0 = MFMA(af, wb[c2], h0);
            }
        }
#pragma unroll
        for (int r = 0; r < 4; ++r) {
            int row = kq * 4 + r;
            regH[(size_t)(r0 + row) * OFT + colh] = f2bf(h0[r]);
        }
    }
    __syncthreads();   // rep boundary: guard Astage/qn_l reuse

    }  // rep

    if (tid == 0) {
        float s = 0.f;
#pragma unroll
        for (int j = 8; j < 16; ++j) s += dlred[j];
        part[b] = s;
    }
}

// ============== k3: fused attention + v1 + v2 (x K3REP) =====================
__global__ __launch_bounds__(1024, 4) void k3_fused(
    const unsigned* __restrict__ KO8, const ushort_t* __restrict__ regH,
    const unsigned* __restrict__ gcols, const int* __restrict__ cnt,
    const ushort_t* __restrict__ Wp, const float* __restrict__ a_v,
    const float* __restrict__ a_act, const float* __restrict__ biasv,
    const float* __restrict__ part, const float* __restrict__ invnk_g,
    float* __restrict__ out)
{
    __shared__ ushort_t csr_c[RPB * CAP];
    __shared__ float    invl[RPB][CAP];
    __shared__ ushort_t Astage[32 * 17 * 8];   // ctx frag layout
    __shared__ ushort_t Hl[32 * 17 * 8];       // h frag layout
    __shared__ float    s8[16];

    const int tid = threadIdx.x, wave = tid >> 6, lane = tid & 63;
    const int t16 = lane & 15, kq = lane >> 4, grp = lane >> 4;
    const int b = blockIdx.x, r0 = b * RPB;
    const size_t batb = (size_t)(b >> 8) * 4096;

    if (b == 0 && tid < 512) {     // div_loss finalize
        float s = part[tid];
#pragma unroll
        for (int off = 32; off; off >>= 1) s += __shfl_down(s, off, 64);
        if (lane == 0) s8[wave] = s;
    }
    __syncthreads();
    if (b == 0 && tid == 0) {
        float t = 0.f;
#pragma unroll
        for (int j = 0; j < 8; ++j) t += s8[j];
        out[(size_t)ROWS * OFT] = t * (1.f / 8192.f);
    }

    {
        unsigned* cc = (unsigned*)csr_c;
        if (tid < RPB * CAP / 2) cc[tid] = gcols[b * (RPB * CAP / 2) + tid];
    }
    __syncthreads();

    for (int rep = 0; rep < K3REP; ++rep) {   // R25 diagnostic repetition

    // ---- attention: wave -> row; 4 edge slots; 2-deep prefetch
    {
        const int row = r0 + wave;
        const int n = cnt[row];
#pragma unroll
        for (int s = 0; s < 2; ++s) {
            int e = lane + s * 64;
            if (e < n) {
                int col = csr_c[wave * CAP + e];
                invl[wave][e] = invnk_g[batb + col] * 0.0625f;
            }
        }
        float q[16];
        {
            const ushort_t* qp = regH + (size_t)row * OFT + t16 * 16;
            uint4 a = *(const uint4*)qp, bq = *(const uint4*)(qp + 8);
            unsigned uu[8] = {a.x, a.y, a.z, a.w, bq.x, bq.y, bq.z, bq.w};
#pragma unroll
            for (int j = 0; j < 8; ++j) { q[2*j] = lo_f(uu[j]); q[2*j+1] = hi_f(uu[j]); }
        }
        const unsigned* gKO = KO8 + batb * 64;
        float c[16];
#pragma unroll
        for (int j = 0; j < 16; ++j) c[j] = 0.f;
        float sE = 0.f;
        const int nIter = (n + 3) >> 2;
        uint4 v0;
        {
            int e0 = grp; int val0 = (e0 < n);
            int col0 = csr_c[wave * CAP + (val0 ? e0 : 0)];
            v0 = *(const uint4*)(gKO + (size_t)col0 * 64 + t16 * 4);
        }
        for (int it = 0; it < nIter; ++it) {
            uint4 n0;
            if (it + 1 < nIter) {
                int e1 = (it + 1) * 4 + grp; int val1 = (e1 < n);
                int col1 = csr_c[wave * CAP + (val1 ? e1 : 0)];
                n0 = *(const uint4*)(gKO + (size_t)col1 * 64 + t16 * 4);
            }
            int e = it * 4 + grp;
            int valid = (e < n);
            float o[16];
            unsigned w4[4] = {v0.x, v0.y, v0.z, v0.w};
#pragma unroll
            for (int i2 = 0; i2 < 4; ++i2) {
                f32x2 x01 = __builtin_amdgcn_cvt_pk_f32_fp8((int)w4[i2], false);
                f32x2 x23 = __builtin_amdgcn_cvt_pk_f32_fp8((int)w4[i2], true);
                o[4*i2+0] = x01.x; o[4*i2+1] = x01.y;
                o[4*i2+2] = x23.x; o[4*i2+3] = x23.y;
            }
            float d = 0.f;
#pragma unroll
            for (int j = 0; j < 16; ++j) d += q[j] * o[j];
            d = dpp_add<0xB1>(d);    // quad xor1
            d = dpp_add<0x4E>(d);    // quad xor2
            d = dpp_add<0x124>(d);   // row_ror:4
            d = dpp_add<0x128>(d);   // row_ror:8
            float iv16v = invl[wave][valid ? e : 0];
            float es = __expf(d * iv16v);   // unscale outb x16 + k-norm
            es = valid ? es : 0.f;
            sE += es;
#pragma unroll
            for (int j = 0; j < 16; ++j) c[j] += es * o[j];
            v0 = n0;
        }
#pragma unroll
        for (int j = 0; j < 16; ++j) {
            c[j] += __shfl_xor(c[j], 16, 64);
            c[j] += __shfl_xor(c[j], 32, 64);
        }
        sE += __shfl_xor(sE, 16, 64);
        sE += __shfl_xor(sE, 32, 64);
        float inv16 = 0.0625f / sE;          // unscale outb x16 + softmax norm
        {
            int d0 = t16 * 16 + grp * 4;
            int q8c = d0 >> 3, off = d0 & 7;
            uint2 st; st.x = pack2(c[grp*4]*inv16, c[grp*4+1]*inv16);
            st.y = pack2(c[grp*4+2]*inv16, c[grp*4+3]*inv16);
            *(uint2*)(Astage + ((size_t)q8c * 17 + wave) * 8 + off) = st;
        }
    }
    __syncthreads();

    // ---- v1 GEMM + PReLU(a_v) -> Hl
    {
        const int col = wave * 16 + t16;
        const ushort_t* Wm = Wp + WP_V1;
        f32x4 h0 = {0.f,0.f,0.f,0.f};
        for (int bch = 0; bch < 2; ++bch) {
            bf16x8 wb[4];
#pragma unroll
            for (int c2 = 0; c2 < 4; ++c2) {
                int k8c = (bch * 4 + c2) * 4 + kq;
                wb[c2] = *(const bf16x8*)(Wm + ((size_t)k8c * 256 + col) * 8);
            }
#pragma unroll
            for (int c2 = 0; c2 < 4; ++c2) {
                int c = bch * 4 + c2;
                bf16x8 af = *(const bf16x8*)(Astage + ((size_t)(c*4 + kq) * 17 + t16) * 8);
                h0 = MFMA(af, wb[c2], h0);
            }
        }
        float av = *a_v;
        int q8c = col >> 3, off = col & 7;
#pragma unroll
        for (int r = 0; r < 4; ++r) {
            int row = kq * 4 + r;
            float x = h0[r]; x = (x >= 0.f) ? x : av * x;
            Hl[((size_t)q8c * 17 + row) * 8 + off] = f2bf(x);
        }
    }
    __syncthreads();

    // ---- v2 GEMM + bias + PReLU(a_act) -> out (fp32)
    {
        const int col = wave * 16 + t16;
        const ushort_t* Wm = Wp + WP_V2;
        f32x4 y0 = {0.f,0.f,0.f,0.f};
        for (int bch = 0; bch < 2; ++bch) {
            bf16x8 wb[4];
#pragma unroll
            for (int c2 = 0; c2 < 4; ++c2) {
                int k8c = (bch * 4 + c2) * 4 + kq;
                wb[c2] = *(const bf16x8*)(Wm + ((size_t)k8c * 256 + col) * 8);
            }
#pragma unroll
            for (int c2 = 0; c2 < 4; ++c2) {
                int c = bch * 4 + c2;
                bf16x8 af = *(const bf16x8*)(Hl + ((size_t)(c*4 + kq) * 17 + t16) * 8);
                y0 = MFMA(af, wb[c2], y0);
            }
        }
        float aa = *a_act;
        float bv = biasv[col];
#pragma unroll
        for (int r = 0; r < 4; ++r) {
            size_t row = (size_t)(r0 + kq * 4 + r);
            float x = y0[r] + bv; x = (x >= 0.f) ? x : aa * x;
            out[row * OFT + col] = x;
        }
    }
    __syncthreads();   // rep boundary: guard Astage/Hl reuse

    }  // rep
}

// ------------------------------------------------------------------- launch
extern "C" void kernel_launch(void* const* d_in, const int* in_sizes, int n_in,
                              void* d_out, int out_size, void* d_ws, size_t ws_size,
                              hipStream_t stream)
{
    const float* seq   = (const float*)d_in[0];
    const float* adj   = (const float*)d_in[1];
    const float* W_fc  = (const float*)d_in[2];
    const float* W_q   = (const float*)d_in[3];
    const float* W_k   = (const float*)d_in[4];
    const float* W_v1  = (const float*)d_in[5];
    const float* W_v2  = (const float*)d_in[6];
    const float* a_v   = (const float*)d_in[7];
    const float* a_act = (const float*)d_in[8];
    const float* bias  = (const float*)d_in[9];

    char* w = (char*)d_ws;
    u8*       regA8 = (u8*)w;                                // seq_fts fp8 2MB
    unsigned* KO8   = (unsigned*)(w + (4u  << 20));          // fp8 outb 2MB
    ushort_t* regH  = (ushort_t*)(w + (12u << 20));          // h=qn.Wk bf16 4MB
    unsigned* gcols = (unsigned*)(w + (16u << 20));          // CSR u16 cols 2MB
    int*      cnt   = (int*)(w + (20u << 20));               // 32KB
    float*    part  = (float*)(w + (20u << 20) + 32768);     // 2KB
    float*    invnk = (float*)(w + (20u << 20) + 65536);     // 32KB
    ushort_t* Wp    = (ushort_t*)(w + (21u << 20));          // 896KB frag weights

    k0_prep<<<224, 256, 0, stream>>>(W_fc, W_q, W_k, W_v1, W_v2, Wp);
    k1_extract_fc<<<NBLK, 1024, 0, stream>>>(seq, adj, Wp, regA8, gcols, cnt);
    k2_spmm_qk<<<NBLK, 1024, 0, stream>>>(regA8, KO8, regH, Wp, gcols, cnt,
                                          part, invnk);
    k3_fused<<<NBLK, 1024, 0, stream>>>(KO8, regH, gcols, cnt, Wp,
                                        a_v, a_act, bias, part, invnk,
                                        (float*)d_out);
}

// Round 8
// 291.059 us; speedup vs baseline: 1.7440x; 1.7440x over previous
//
#include <hip/hip_runtime.h>
#include <hip/hip_bf16.h>

// GCN attention forward, MI355X. fp32 inputs (counter-proven R14).
// R25 counters (k2 x4): VALU 26%, Mfma 3%, Occ 45%, FETCH 258MB/dispatch
// vs ~4MB working set -> gathers MISS L2 always; kernel time ~= gather
// bytes / ~2.4TB/s fabric rate. Explains R18/R20/R22/R24 nulls.
// R26: dim-sliced spmm. k2a: 512 blocks = 64 row-groups x 8 dim-slices;
// slice s = blockIdx%8 -> XCD s (round-robin dispatch), so each XCD
// gathers only its 32-dim slice of regA8 (~1MB lines) -> L2-resident.
// k2a writes KO8 fp8 (k3-compatible chunk layout) + outB16 bf16.
// k2b: q/k GEMM + norm + loss + h-GEMM, staging Astage densely from
// outB16 (numerics identical to R22). k3 unchanged (ports next if WIN).
// k0 Wprep | k1 extract+fc | k2a spmm-sliced | k2b qk+h | k3 attn+v1+v2.

#define NN    4096
#define ROWS  8192
#define OFT   256
#define CAP   128
#define NBLK  512
#define RPB   16
#define QLS   264   // qn_l row stride (ushort) — bank-spread for h-GEMM reads
#define EPSN  1e-12f
#define MFMA(a,b,c) __builtin_amdgcn_mfma_f32_16x16x32_bf16((a),(b),(c),0,0,0)

typedef unsigned short ushort_t;
typedef unsigned char  u8;
typedef __attribute__((ext_vector_type(8))) short bf16x8;
typedef __attribute__((ext_vector_type(4))) float f32x4;
typedef __attribute__((ext_vector_type(2))) float f32x2;

#define WP_FC   0
#define WP_Q    (16384 * 8)
#define WP_K    (WP_Q + 8192 * 8)
#define WP_V1   (WP_K + 8192 * 8)
#define WP_V2   (WP_V1 + 8192 * 8)
#define WP_KT   (WP_V2 + 8192 * 8)   // Wk transposed frags: [p-kmajor][o-col]

__device__ __forceinline__ float lo_f(unsigned u) { union { unsigned i; float f; } c; c.i = u << 16;          return c.f; }
__device__ __forceinline__ float hi_f(unsigned u) { union { unsigned i; float f; } c; c.i = u & 0xFFFF0000u;  return c.f; }
__device__ __forceinline__ float bf2f(ushort_t u) { union { unsigned i; float f; } c; c.i = (unsigned)u << 16; return c.f; }
__device__ __forceinline__ ushort_t f2bf(float f) {
    union { float f; unsigned i; } c; c.f = f;
    unsigned r = c.i + 0x7FFFu + ((c.i >> 16) & 1u);
    return (ushort_t)(r >> 16);
}
__device__ __forceinline__ unsigned pack2(float a, float b) {
    return (unsigned)f2bf(a) | ((unsigned)f2bf(b) << 16);
}

template<int CTRL>
__device__ __forceinline__ float dpp_add(float x) {
    union { float f; int i; } c; c.f = x;
    int y = __builtin_amdgcn_update_dpp(c.i, c.i, CTRL, 0xF, 0xF, false);
    union { int i; float f; } r; r.i = y;
    return x + r.f;
}

// ===================== k0: weight prep -> bf16 frag layout ==================
__global__ __launch_bounds__(256) void k0_prep(
    const float* __restrict__ Wfc, const float* __restrict__ Wq,
    const float* __restrict__ Wk,  const float* __restrict__ Wv1,
    const float* __restrict__ Wv2, ushort_t* __restrict__ Wp)
{
    int sid = blockIdx.x * 256 + threadIdx.x;
    if (sid >= 49152) {            // WkT: frag (p8, col=o): Wk[p8*8+i][o]
        int t = sid - 49152;       // 0..8191
        int o = t & 255, p8 = t >> 8;
        ushort_t tmp[8];
#pragma unroll
        for (int i = 0; i < 8; ++i)
            tmp[i] = f2bf(Wk[(size_t)(p8 * 8 + i) * 256 + o]);
        *(bf16x8*)(Wp + WP_KT + (size_t)t * 8) = *(bf16x8*)tmp;
        return;
    }
    const float* src; int K, local; ushort_t* dst;
    if (sid < 16384) { src = Wfc; K = 512; local = sid; dst = Wp + WP_FC + (size_t)local * 8; }
    else {
        int s = sid - 16384, which = s >> 13; local = s & 8191;
        const float* ws4[4] = {Wq, Wk, Wv1, Wv2};
        src = ws4[which]; K = 256;
        dst = Wp + WP_Q + (size_t)which * 65536 + (size_t)local * 8;
    }
    int col = local & 255, k8c = local >> 8;
    const float* p = src + (size_t)col * K + k8c * 8;
    float4 x0 = *(const float4*)p, x1 = *(const float4*)(p + 4);
    uint4 o; o.x = pack2(x0.x, x0.y); o.y = pack2(x0.z, x0.w);
    o.z = pack2(x1.x, x1.y); o.w = pack2(x1.z, x1.w);
    *(uint4*)dst = o;
}

// ============================ k1: extract + fc ==============================
__global__ __launch_bounds__(1024, 4) void k1_extract_fc(
    const float* __restrict__ seq, const float* __restrict__ adj,
    const ushort_t* __restrict__ Wp, u8* __restrict__ regA8,
    unsigned* __restrict__ gcols, int* __restrict__ cnt)
{
    __shared__ ushort_t Astage[64 * 17 * 8];
    __shared__ ushort_t csr_c[RPB * CAP];
    __shared__ int      csr_n[RPB];

    const int tid = threadIdx.x, wave = tid >> 6, lane = tid & 63;
    const int t16 = lane & 15, kq = lane >> 4;
    const int b = blockIdx.x, r0 = b * RPB;

    {   // extract: wave -> row; all 16 float4 loads up-front
        const float4* rowp = (const float4*)(adj + (size_t)(r0 + wave) * NN);
        float4 v[16];
#pragma unroll
        for (int t = 0; t < 16; ++t) v[t] = rowp[t * 64 + lane];
        int base = 0;
#pragma unroll
        for (int h = 0; h < 2; ++h) {
            int c = 0;
#pragma unroll
            for (int t = 0; t < 8; ++t) {
                const float4& x = v[h * 8 + t];
                c += (x.x > 0.f) + (x.y > 0.f) + (x.z > 0.f) + (x.w > 0.f);
            }
            int incl = c;
#pragma unroll
            for (int off = 1; off < 64; off <<= 1) {
                int y = __shfl_up(incl, off, 64);
                if (lane >= off) incl += y;
            }
            int p = base + incl - c;
            base += __shfl(incl, 63, 64);
#pragma unroll
            for (int t = 0; t < 8; ++t) {
                const float4& x = v[h * 8 + t];
                float f[4] = {x.x, x.y, x.z, x.w};
#pragma unroll
                for (int j = 0; j < 4; ++j)
                    if (f[j] > 0.f) {
                        if (p < CAP)
                            csr_c[wave * CAP + p] = (ushort_t)(((h * 8 + t) * 64 + lane) * 4 + j);
                        ++p;
                    }
            }
        }
        if (lane == 0) csr_n[wave] = (base < CAP) ? base : CAP;
    }
    __syncthreads();
    {
        const unsigned* cc = (const unsigned*)csr_c;
        if (tid < RPB * CAP / 2) gcols[b * (RPB * CAP / 2) + tid] = cc[tid];
        if (tid < RPB) cnt[r0 + tid] = csr_n[tid];
    }

    // ---- stage seq 16 x 512 (fp32 -> bf16, k-major frag layout)
    {
        int row = tid >> 6, seg = tid & 63;
        const float* p = seq + (size_t)(r0 + row) * 512 + seg * 8;
        float4 x0 = *(const float4*)p, x1 = *(const float4*)(p + 4);
        uint4 a;
        a.x = pack2(x0.x, x0.y); a.y = pack2(x0.z, x0.w);
        a.z = pack2(x1.x, x1.y); a.w = pack2(x1.z, x1.w);
        *(bf16x8*)(Astage + ((size_t)seg * 17 + row) * 8) = *(bf16x8*)&a;
    }
    __syncthreads();

    // ---- fc GEMM: wave -> 16 cols; epilogue -> fp8 x16 byte stores
    {
        const int col = wave * 16 + t16;
        const ushort_t* Wm = Wp + WP_FC;
        f32x4 a0 = {0.f, 0.f, 0.f, 0.f};
        for (int bch = 0; bch < 4; ++bch) {
            bf16x8 wb[4];
#pragma unroll
            for (int c2 = 0; c2 < 4; ++c2) {
                int k8c = (bch * 4 + c2) * 4 + kq;
                wb[c2] = *(const bf16x8*)(Wm + ((size_t)k8c * 256 + col) * 8);
            }
#pragma unroll
            for (int c2 = 0; c2 < 4; ++c2) {
                int c = bch * 4 + c2;
                bf16x8 af = *(const bf16x8*)(Astage + ((size_t)(c * 4 + kq) * 17 + t16) * 8);
                a0 = MFMA(af, wb[c2], a0);
            }
        }
#pragma unroll
        for (int r = 0; r < 4; ++r) {
            int t8 = __builtin_amdgcn_cvt_pk_fp8_f32(a0[r] * 16.f, 0.f, 0, false);
            regA8[(size_t)(r0 + kq * 4 + r) * OFT + col] = (u8)(t8 & 0xFF);
        }
    }
}

// ================= k2a: dim-sliced spmm (64 row-grp x 8 slices) =============
// Block (g = b>>3, s = b&7): rows g*128..+127, dims s*32..+31. With %8
// round-robin dispatch, XCD s only ever touches its 32-dim slice of
// regA8 -> per-XCD gather working set ~1MB of lines -> L2-resident.
// Lane: e8 = lane>>3 (edge slot), l8 = lane&7 (4-dim quarter of slice).
__global__ __launch_bounds__(1024, 4) void k2a_spmm(
    const u8* __restrict__ regA8, unsigned* __restrict__ KO8,
    ushort_t* __restrict__ outB16,
    const unsigned* __restrict__ gcols, const int* __restrict__ cnt)
{
    __shared__ ushort_t csr_c[128 * CAP];   // 32 KB
    __shared__ int      cnt_l[128];

    const int tid = threadIdx.x, wave = tid >> 6, lane = tid & 63;
    const int e8 = lane >> 3, l8 = lane & 7;
    const int b = blockIdx.x;
    const int g = b >> 3, s = b & 7;
    const int r0 = g * 128;
    const size_t batb = (size_t)(r0 >> 12) * 4096;

    {   // stage CSR for 128 rows (8 contiguous 16-row groups in gcols)
        unsigned* cc = (unsigned*)csr_c;
        const unsigned* src = gcols + (size_t)(g * 8) * 1024;
#pragma unroll
        for (int i = 0; i < 8; ++i) cc[tid + i * 1024] = src[tid + i * 1024];
        if (tid < 128) cnt_l[tid] = cnt[r0 + tid];
    }
    __syncthreads();

    const u8* gA = regA8 + batb * OFT + s * 32 + l8 * 4;
    for (int r8 = 0; r8 < 8; ++r8) {
        const int lrow = wave * 8 + r8;
        const int n = cnt_l[lrow];
        float a0 = 0.f, a1 = 0.f, a2 = 0.f, a3 = 0.f;
        const int nIt = (n + 7) >> 3;
        unsigned v;
        {
            int e = e8;
            int col = csr_c[lrow * CAP + (e < n ? e : 0)];
            v = *(const unsigned*)(gA + (size_t)col * OFT);
        }
        for (int it = 0; it < nIt; ++it) {
            unsigned vn = 0;
            if (it + 1 < nIt) {
                int e = (it + 1) * 8 + e8;
                int col = csr_c[lrow * CAP + (e < n ? e : 0)];
                vn = *(const unsigned*)(gA + (size_t)col * OFT);
            }
            int e = it * 8 + e8;
            if (e < n) {
                f32x2 lo = __builtin_amdgcn_cvt_pk_f32_fp8((int)v, false);
                f32x2 hi = __builtin_amdgcn_cvt_pk_f32_fp8((int)v, true);
                a0 += lo.x; a1 += lo.y; a2 += hi.x; a3 += hi.y;
            }
            v = vn;
        }
#pragma unroll
        for (int m = 8; m < 64; m <<= 1) {
            a0 += __shfl_xor(a0, m, 64); a1 += __shfl_xor(a1, m, 64);
            a2 += __shfl_xor(a2, m, 64); a3 += __shfl_xor(a3, m, 64);
        }
        if (lane < 8) {
            float iv = 1.f / (16.f * (float)max(n, 1));
            float o0 = a0 * iv, o1 = a1 * iv, o2 = a2 * iv, o3 = a3 * iv;
            int row = r0 + lrow;
            int uo = 0;
            uo = __builtin_amdgcn_cvt_pk_fp8_f32(o0 * 16.f, o1 * 16.f, uo, false);
            uo = __builtin_amdgcn_cvt_pk_fp8_f32(o2 * 16.f, o3 * 16.f, uo, true);
            // chunk layout matches k3's reader: dword 8s+l8 <-> dims s*32+l8*4
            KO8[(size_t)row * 64 + s * 8 + l8] = (unsigned)uo;
            uint2 st; st.x = pack2(o0, o1); st.y = pack2(o2, o3);
            *(uint2*)(outB16 + (size_t)row * 256 + s * 32 + l8 * 4) = st;
        }
    }
}

// ============== k2b: q/k GEMM + norm + loss + h-GEMM (from outB16) ==========
__global__ __launch_bounds__(1024, 4) void k2b_qk(
    const ushort_t* __restrict__ outB16, ushort_t* __restrict__ regH,
    const ushort_t* __restrict__ Wp, float* __restrict__ part,
    float* __restrict__ invnk_g)
{
    __shared__ ushort_t Astage[32 * 17 * 8];
    __shared__ ushort_t qn_l[RPB * QLS];
    __shared__ float    red[2][RPB][8];
    __shared__ float    dlred[16];

    const int tid = threadIdx.x, wave = tid >> 6, lane = tid & 63;
    const int t16 = lane & 15, kq = lane >> 4;
    const int b = blockIdx.x, r0 = b * RPB;

    {   // stage out 16 x 256 bf16 -> Astage frag layout (dense read)
        int rl = tid >> 6, seg = tid & 63;
        if (seg < 32) {
            uint4 a = *(const uint4*)(outB16 + (size_t)(r0 + rl) * 256 + seg * 8);
            *(bf16x8*)(Astage + ((size_t)seg * 17 + rl) * 8) = *(bf16x8*)&a;
        }
    }
    __syncthreads();

    // ---- q/k GEMM: waves 0-7 q, 8-15 k; wave -> 32 cols
    const int isK = wave >> 3, w8 = wave & 7;
    const ushort_t* Wm = Wp + (isK ? WP_K : WP_Q);
    f32x4 acc[2];
    acc[0] = (f32x4){0.f,0.f,0.f,0.f};
    acc[1] = (f32x4){0.f,0.f,0.f,0.f};
    for (int bch = 0; bch < 2; ++bch) {
        bf16x8 wb[2][4];
#pragma unroll
        for (int j = 0; j < 2; ++j)
#pragma unroll
            for (int c2 = 0; c2 < 4; ++c2) {
                int col = w8 * 32 + j * 16 + t16;
                int k8c = (bch * 4 + c2) * 4 + kq;
                wb[j][c2] = *(const bf16x8*)(Wm + ((size_t)k8c * 256 + col) * 8);
            }
#pragma unroll
        for (int c2 = 0; c2 < 4; ++c2) {
            int c = bch * 4 + c2;
            bf16x8 af = *(const bf16x8*)(Astage + ((size_t)(c*4 + kq) * 17 + t16) * 8);
            acc[0] = MFMA(af, wb[0][c2], acc[0]);
            acc[1] = MFMA(af, wb[1][c2], acc[1]);
        }
    }
#pragma unroll
    for (int r = 0; r < 4; ++r) {
        float s = acc[0][r]*acc[0][r] + acc[1][r]*acc[1][r];
#pragma unroll
        for (int off = 1; off < 16; off <<= 1) s += __shfl_xor(s, off, 16);
        if (t16 == 0) red[isK][kq*4 + r][w8] = s;
    }
    __syncthreads();
#pragma unroll
    for (int r = 0; r < 4; ++r) {
        int row = kq * 4 + r;
        float s = 0.f;
#pragma unroll
        for (int j = 0; j < 8; ++j) s += red[isK][row][j];
        float inv = 1.f / fmaxf(sqrtf(s), EPSN);
        if (isK && w8 == 0 && t16 == 0) invnk_g[r0 + row] = inv;
#pragma unroll
        for (int j = 0; j < 2; ++j) {
            int col = w8 * 32 + j * 16 + t16;
            float v = acc[j][r] * inv;
            acc[j][r] = v;
            if (!isK) qn_l[row * QLS + col] = f2bf(v);
        }
    }
    __syncthreads();
    if (isK) {
        float dl = 0.f;
#pragma unroll
        for (int r = 0; r < 4; ++r) {
            int row = kq * 4 + r;
#pragma unroll
            for (int j = 0; j < 2; ++j) {
                int col = w8 * 32 + j * 16 + t16;
                float d = bf2f(qn_l[row * QLS + col]) - acc[j][r];
                dl += d * d;
            }
        }
#pragma unroll
        for (int off = 1; off < 64; off <<= 1) dl += __shfl_xor(dl, off, 64);
        if (lane == 0) dlred[wave] = dl;
    }
    __syncthreads();

    // ---- h-GEMM: h[m] = qn[m] . Wk via WP_KT; 16 waves x 16 cols
    {
        const ushort_t* WmT = Wp + WP_KT;
        const int colh = wave * 16 + t16;
        f32x4 h0 = {0.f, 0.f, 0.f, 0.f};
        for (int bch = 0; bch < 2; ++bch) {
            bf16x8 wb[4];
#pragma unroll
            for (int c2 = 0; c2 < 4; ++c2) {
                int k8c = (bch * 4 + c2) * 4 + kq;
                wb[c2] = *(const bf16x8*)(WmT + ((size_t)k8c * 256 + colh) * 8);
            }
#pragma unroll
            for (int c2 = 0; c2 < 4; ++c2) {
                int k8c = (bch * 4 + c2) * 4 + kq;
                bf16x8 af = *(const bf16x8*)(qn_l + (size_t)t16 * QLS + k8c * 8);
                h0 = MFMA(af, wb[c2], h0);
            }
        }
#pragma unroll
        for (int r = 0; r < 4; ++r) {
            int row = kq * 4 + r;
            regH[(size_t)(r0 + row) * OFT + colh] = f2bf(h0[r]);
        }
    }
    if (tid == 0) {
        float s = 0.f;
#pragma unroll
        for (int j = 8; j < 16; ++j) s += dlred[j];
        part[b] = s;
    }
}

// ============== k3: fused attention + v1 + v2 (16 waves, 16 rows) ===========
__global__ __launch_bounds__(1024, 4) void k3_fused(
    const unsigned* __restrict__ KO8, const ushort_t* __restrict__ regH,
    const unsigned* __restrict__ gcols, const int* __restrict__ cnt,
    const ushort_t* __restrict__ Wp, const float* __restrict__ a_v,
    const float* __restrict__ a_act, const float* __restrict__ biasv,
    const float* __restrict__ part, const float* __restrict__ invnk_g,
    float* __restrict__ out)
{
    __shared__ ushort_t csr_c[RPB * CAP];
    __shared__ float    invl[RPB][CAP];
    __shared__ ushort_t Astage[32 * 17 * 8];   // ctx frag layout
    __shared__ ushort_t Hl[32 * 17 * 8];       // h frag layout
    __shared__ float    s8[16];

    const int tid = threadIdx.x, wave = tid >> 6, lane = tid & 63;
    const int t16 = lane & 15, kq = lane >> 4, grp = lane >> 4;
    const int b = blockIdx.x, r0 = b * RPB;
    const size_t batb = (size_t)(b >> 8) * 4096;

    if (b == 0 && tid < 512) {     // div_loss finalize
        float s = part[tid];
#pragma unroll
        for (int off = 32; off; off >>= 1) s += __shfl_down(s, off, 64);
        if (lane == 0) s8[wave] = s;
    }
    __syncthreads();
    if (b == 0 && tid == 0) {
        float t = 0.f;
#pragma unroll
        for (int j = 0; j < 8; ++j) t += s8[j];
        out[(size_t)ROWS * OFT] = t * (1.f / 8192.f);
    }

    {
        unsigned* cc = (unsigned*)csr_c;
        if (tid < RPB * CAP / 2) cc[tid] = gcols[b * (RPB * CAP / 2) + tid];
    }
    __syncthreads();

    // ---- attention: wave -> row; 4 edge slots; 2-deep prefetch
    {
        const int row = r0 + wave;
        const int n = cnt[row];
#pragma unroll
        for (int s = 0; s < 2; ++s) {
            int e = lane + s * 64;
            if (e < n) {
                int col = csr_c[wave * CAP + e];
                invl[wave][e] = invnk_g[batb + col] * 0.0625f;
            }
        }
        float q[16];
        {
            const ushort_t* qp = regH + (size_t)row * OFT + t16 * 16;
            uint4 a = *(const uint4*)qp, bq = *(const uint4*)(qp + 8);
            unsigned uu[8] = {a.x, a.y, a.z, a.w, bq.x, bq.y, bq.z, bq.w};
#pragma unroll
            for (int j = 0; j < 8; ++j) { q[2*j] = lo_f(uu[j]); q[2*j+1] = hi_f(uu[j]); }
        }
        const unsigned* gKO = KO8 + batb * 64;
        float c[16];
#pragma unroll
        for (int j = 0; j < 16; ++j) c[j] = 0.f;
        float sE = 0.f;
        const int nIter = (n + 3) >> 2;
        uint4 v0;
        {
            int e0 = grp; int val0 = (e0 < n);
            int col0 = csr_c[wave * CAP + (val0 ? e0 : 0)];
            v0 = *(const uint4*)(gKO + (size_t)col0 * 64 + t16 * 4);
        }
        for (int it = 0; it < nIter; ++it) {
            uint4 n0;
            if (it + 1 < nIter) {
                int e1 = (it + 1) * 4 + grp; int val1 = (e1 < n);
                int col1 = csr_c[wave * CAP + (val1 ? e1 : 0)];
                n0 = *(const uint4*)(gKO + (size_t)col1 * 64 + t16 * 4);
            }
            int e = it * 4 + grp;
            int valid = (e < n);
            float o[16];
            unsigned w4[4] = {v0.x, v0.y, v0.z, v0.w};
#pragma unroll
            for (int i2 = 0; i2 < 4; ++i2) {
                f32x2 x01 = __builtin_amdgcn_cvt_pk_f32_fp8((int)w4[i2], false);
                f32x2 x23 = __builtin_amdgcn_cvt_pk_f32_fp8((int)w4[i2], true);
                o[4*i2+0] = x01.x; o[4*i2+1] = x01.y;
                o[4*i2+2] = x23.x; o[4*i2+3] = x23.y;
            }
            float d = 0.f;
#pragma unroll
            for (int j = 0; j < 16; ++j) d += q[j] * o[j];
            d = dpp_add<0xB1>(d);    // quad xor1
            d = dpp_add<0x4E>(d);    // quad xor2
            d = dpp_add<0x124>(d);   // row_ror:4
            d = dpp_add<0x128>(d);   // row_ror:8
            float iv16v = invl[wave][valid ? e : 0];
            float es = __expf(d * iv16v);   // unscale outb x16 + k-norm
            es = valid ? es : 0.f;
            sE += es;
#pragma unroll
            for (int j = 0; j < 16; ++j) c[j] += es * o[j];
            v0 = n0;
        }
#pragma unroll
        for (int j = 0; j < 16; ++j) {
            c[j] += __shfl_xor(c[j], 16, 64);
            c[j] += __shfl_xor(c[j], 32, 64);
        }
        sE += __shfl_xor(sE, 16, 64);
        sE += __shfl_xor(sE, 32, 64);
        float inv16 = 0.0625f / sE;          // unscale outb x16 + softmax norm
        {
            int d0 = t16 * 16 + grp * 4;
            int q8c = d0 >> 3, off = d0 & 7;
            uint2 st; st.x = pack2(c[grp*4]*inv16, c[grp*4+1]*inv16);
            st.y = pack2(c[grp*4+2]*inv16, c[grp*4+3]*inv16);
            *(uint2*)(Astage + ((size_t)q8c * 17 + wave) * 8 + off) = st;
        }
    }
    __syncthreads();

    // ---- v1 GEMM + PReLU(a_v) -> Hl
    const int col = wave * 16 + t16;
    {
        const ushort_t* Wm = Wp + WP_V1;
        f32x4 h0 = {0.f,0.f,0.f,0.f};
        for (int bch = 0; bch < 2; ++bch) {
            bf16x8 wb[4];
#pragma unroll
            for (int c2 = 0; c2 < 4; ++c2) {
                int k8c = (bch * 4 + c2) * 4 + kq;
                wb[c2] = *(const bf16x8*)(Wm + ((size_t)k8c * 256 + col) * 8);
            }
#pragma unroll
            for (int c2 = 0; c2 < 4; ++c2) {
                int c = bch * 4 + c2;
                bf16x8 af = *(const bf16x8*)(Astage + ((size_t)(c*4 + kq) * 17 + t16) * 8);
                h0 = MFMA(af, wb[c2], h0);
            }
        }
        float av = *a_v;
        int q8c = col >> 3, off = col & 7;
#pragma unroll
        for (int r = 0; r < 4; ++r) {
            int row = kq * 4 + r;
            float x = h0[r]; x = (x >= 0.f) ? x : av * x;
            Hl[((size_t)q8c * 17 + row) * 8 + off] = f2bf(x);
        }
    }
    __syncthreads();

    // ---- v2 GEMM + bias + PReLU(a_act) -> out (fp32)
    {
        const ushort_t* Wm = Wp + WP_V2;
        f32x4 y0 = {0.f,0.f,0.f,0.f};
        for (int bch = 0; bch < 2; ++bch) {
            bf16x8 wb[4];
#pragma unroll
            for (int c2 = 0; c2 < 4; ++c2) {
                int k8c = (bch * 4 + c2) * 4 + kq;
                wb[c2] = *(const bf16x8*)(Wm + ((size_t)k8c * 256 + col) * 8);
            }
#pragma unroll
            for (int c2 = 0; c2 < 4; ++c2) {
                int c = bch * 4 + c2;
                bf16x8 af = *(const bf16x8*)(Hl + ((size_t)(c*4 + kq) * 17 + t16) * 8);
                y0 = MFMA(af, wb[c2], y0);
            }
        }
        float aa = *a_act;
        float bv = biasv[col];
#pragma unroll
        for (int r = 0; r < 4; ++r) {
            size_t row = (size_t)(r0 + kq * 4 + r);
            float x = y0[r] + bv; x = (x >= 0.f) ? x : aa * x;
            out[row * OFT + col] = x;
        }
    }
}

// ------------------------------------------------------------------- launch
extern "C" void kernel_launch(void* const* d_in, const int* in_sizes, int n_in,
                              void* d_out, int out_size, void* d_ws, size_t ws_size,
                              hipStream_t stream)
{
    const float* seq   = (const float*)d_in[0];
    const float* adj   = (const float*)d_in[1];
    const float* W_fc  = (const float*)d_in[2];
    const float* W_q   = (const float*)d_in[3];
    const float* W_k   = (const float*)d_in[4];
    const float* W_v1  = (const float*)d_in[5];
    const float* W_v2  = (const float*)d_in[6];
    const float* a_v   = (const float*)d_in[7];
    const float* a_act = (const float*)d_in[8];
    const float* bias  = (const float*)d_in[9];

    char* w = (char*)d_ws;
    u8*       regA8  = (u8*)w;                               // seq_fts fp8 2MB
    unsigned* KO8    = (unsigned*)(w + (4u  << 20));         // fp8 outb 2MB
    ushort_t* regH   = (ushort_t*)(w + (12u << 20));         // h=qn.Wk bf16 4MB
    unsigned* gcols  = (unsigned*)(w + (16u << 20));         // CSR u16 cols 2MB
    int*      cnt    = (int*)(w + (20u << 20));              // 32KB
    float*    part   = (float*)(w + (20u << 20) + 32768);    // 2KB
    float*    invnk  = (float*)(w + (20u << 20) + 65536);    // 32KB
    ushort_t* Wp     = (ushort_t*)(w + (21u << 20));         // 896KB frag weights
    ushort_t* outB16 = (ushort_t*)(w + (24u << 20));         // out bf16 4MB

    k0_prep<<<224, 256, 0, stream>>>(W_fc, W_q, W_k, W_v1, W_v2, Wp);
    k1_extract_fc<<<NBLK, 1024, 0, stream>>>(seq, adj, Wp, regA8, gcols, cnt);
    k2a_spmm<<<NBLK, 1024, 0, stream>>>(regA8, KO8, outB16, gcols, cnt);
    k2b_qk<<<NBLK, 1024, 0, stream>>>(outB16, regH, Wp, part, invnk);
    k3_fused<<<NBLK, 1024, 0, stream>>>(KO8, regH, gcols, cnt, Wp,
                                        a_v, a_act, bias, part, invnk,
                                        (float*)d_out);
}

// Round 9
// 275.522 us; speedup vs baseline: 1.8424x; 1.0564x over previous
//
#include <hip/hip_runtime.h>
#include <hip/hip_bf16.h>

// GCN attention forward, MI355X. fp32 inputs (counter-proven R14).
// R25 counters: k2 gather FETCH 64.5MB/rep vs 2MB/batch buffer -> L2
// thrash. Cause: both batches run on every XCD (round-robin dispatch),
// so per-XCD working set = 4MB regA8 + ~0.4MB Wp + ~0.8MB write streams
// > 4MiB L2. R26 (dim-slice) FAILED +16us: 4x requests + line waste +
// extra pass buried the mechanism. R27: exact R22 code + batch->XCD-group
// block remap in k2/k3 (xcd=b&7; bat=xcd>>2; idx=(b>>3)*4+(xcd&3)):
// XCDs 0-3 gather only batch 0, XCDs 4-7 only batch 1 -> per-XCD read
// set 2MB(k2)/1MB(k3) -> L2-resident. Bijective; arithmetic unchanged;
// degrades to status quo if %8->XCD mapping is wrong.
// k0 Wprep(+WkT) | k1 extract+fc(fp8) | k2 spmm+qk+h | k3 attn+v1+v2.

#define NN    4096
#define ROWS  8192
#define OFT   256
#define CAP   128
#define NBLK  512
#define RPB   16
#define QLS   264   // qn_l row stride (ushort) — bank-spread for h-GEMM reads
#define EPSN  1e-12f
#define MFMA(a,b,c) __builtin_amdgcn_mfma_f32_16x16x32_bf16((a),(b),(c),0,0,0)

typedef unsigned short ushort_t;
typedef unsigned char  u8;
typedef __attribute__((ext_vector_type(8))) short bf16x8;
typedef __attribute__((ext_vector_type(4))) float f32x4;
typedef __attribute__((ext_vector_type(2))) float f32x2;

#define WP_FC   0
#define WP_Q    (16384 * 8)
#define WP_K    (WP_Q + 8192 * 8)
#define WP_V1   (WP_K + 8192 * 8)
#define WP_V2   (WP_V1 + 8192 * 8)
#define WP_KT   (WP_V2 + 8192 * 8)   // Wk transposed frags: [p-kmajor][o-col]

__device__ __forceinline__ float lo_f(unsigned u) { union { unsigned i; float f; } c; c.i = u << 16;          return c.f; }
__device__ __forceinline__ float hi_f(unsigned u) { union { unsigned i; float f; } c; c.i = u & 0xFFFF0000u;  return c.f; }
__device__ __forceinline__ float bf2f(ushort_t u) { union { unsigned i; float f; } c; c.i = (unsigned)u << 16; return c.f; }
__device__ __forceinline__ ushort_t f2bf(float f) {
    union { float f; unsigned i; } c; c.f = f;
    unsigned r = c.i + 0x7FFFu + ((c.i >> 16) & 1u);
    return (ushort_t)(r >> 16);
}
__device__ __forceinline__ unsigned pack2(float a, float b) {
    return (unsigned)f2bf(a) | ((unsigned)f2bf(b) << 16);
}

template<int CTRL>
__device__ __forceinline__ float dpp_add(float x) {
    union { float f; int i; } c; c.f = x;
    int y = __builtin_amdgcn_update_dpp(c.i, c.i, CTRL, 0xF, 0xF, false);
    union { int i; float f; } r; r.i = y;
    return x + r.f;
}

// ===================== k0: weight prep -> bf16 frag layout ==================
__global__ __launch_bounds__(256) void k0_prep(
    const float* __restrict__ Wfc, const float* __restrict__ Wq,
    const float* __restrict__ Wk,  const float* __restrict__ Wv1,
    const float* __restrict__ Wv2, ushort_t* __restrict__ Wp)
{
    int sid = blockIdx.x * 256 + threadIdx.x;
    if (sid >= 49152) {            // WkT: frag (p8, col=o): Wk[p8*8+i][o]
        int t = sid - 49152;       // 0..8191
        int o = t & 255, p8 = t >> 8;
        ushort_t tmp[8];
#pragma unroll
        for (int i = 0; i < 8; ++i)
            tmp[i] = f2bf(Wk[(size_t)(p8 * 8 + i) * 256 + o]);
        *(bf16x8*)(Wp + WP_KT + (size_t)t * 8) = *(bf16x8*)tmp;
        return;
    }
    const float* src; int K, local; ushort_t* dst;
    if (sid < 16384) { src = Wfc; K = 512; local = sid; dst = Wp + WP_FC + (size_t)local * 8; }
    else {
        int s = sid - 16384, which = s >> 13; local = s & 8191;
        const float* ws4[4] = {Wq, Wk, Wv1, Wv2};
        src = ws4[which]; K = 256;
        dst = Wp + WP_Q + (size_t)which * 65536 + (size_t)local * 8;
    }
    int col = local & 255, k8c = local >> 8;
    const float* p = src + (size_t)col * K + k8c * 8;
    float4 x0 = *(const float4*)p, x1 = *(const float4*)(p + 4);
    uint4 o; o.x = pack2(x0.x, x0.y); o.y = pack2(x0.z, x0.w);
    o.z = pack2(x1.x, x1.y); o.w = pack2(x1.z, x1.w);
    *(uint4*)dst = o;
}

// ============================ k1: extract + fc ==============================
__global__ __launch_bounds__(1024, 4) void k1_extract_fc(
    const float* __restrict__ seq, const float* __restrict__ adj,
    const ushort_t* __restrict__ Wp, u8* __restrict__ regA8,
    unsigned* __restrict__ gcols, int* __restrict__ cnt)
{
    __shared__ ushort_t Astage[64 * 17 * 8];
    __shared__ ushort_t csr_c[RPB * CAP];
    __shared__ int      csr_n[RPB];

    const int tid = threadIdx.x, wave = tid >> 6, lane = tid & 63;
    const int t16 = lane & 15, kq = lane >> 4;
    const int b = blockIdx.x, r0 = b * RPB;

    {   // extract: wave -> row; all 16 float4 loads up-front
        const float4* rowp = (const float4*)(adj + (size_t)(r0 + wave) * NN);
        float4 v[16];
#pragma unroll
        for (int t = 0; t < 16; ++t) v[t] = rowp[t * 64 + lane];
        int base = 0;
#pragma unroll
        for (int h = 0; h < 2; ++h) {
            int c = 0;
#pragma unroll
            for (int t = 0; t < 8; ++t) {
                const float4& x = v[h * 8 + t];
                c += (x.x > 0.f) + (x.y > 0.f) + (x.z > 0.f) + (x.w > 0.f);
            }
            int incl = c;
#pragma unroll
            for (int off = 1; off < 64; off <<= 1) {
                int y = __shfl_up(incl, off, 64);
                if (lane >= off) incl += y;
            }
            int p = base + incl - c;
            base += __shfl(incl, 63, 64);
#pragma unroll
            for (int t = 0; t < 8; ++t) {
                const float4& x = v[h * 8 + t];
                float f[4] = {x.x, x.y, x.z, x.w};
#pragma unroll
                for (int j = 0; j < 4; ++j)
                    if (f[j] > 0.f) {
                        if (p < CAP)
                            csr_c[wave * CAP + p] = (ushort_t)(((h * 8 + t) * 64 + lane) * 4 + j);
                        ++p;
                    }
            }
        }
        if (lane == 0) csr_n[wave] = (base < CAP) ? base : CAP;
    }
    __syncthreads();
    {
        const unsigned* cc = (const unsigned*)csr_c;
        if (tid < RPB * CAP / 2) gcols[b * (RPB * CAP / 2) + tid] = cc[tid];
        if (tid < RPB) cnt[r0 + tid] = csr_n[tid];
    }

    // ---- stage seq 16 x 512 (fp32 -> bf16, k-major frag layout)
    {
        int row = tid >> 6, seg = tid & 63;
        const float* p = seq + (size_t)(r0 + row) * 512 + seg * 8;
        float4 x0 = *(const float4*)p, x1 = *(const float4*)(p + 4);
        uint4 a;
        a.x = pack2(x0.x, x0.y); a.y = pack2(x0.z, x0.w);
        a.z = pack2(x1.x, x1.y); a.w = pack2(x1.z, x1.w);
        *(bf16x8*)(Astage + ((size_t)seg * 17 + row) * 8) = *(bf16x8*)&a;
    }
    __syncthreads();

    // ---- fc GEMM: wave -> 16 cols; epilogue -> fp8 x16 byte stores
    {
        const int col = wave * 16 + t16;
        const ushort_t* Wm = Wp + WP_FC;
        f32x4 a0 = {0.f, 0.f, 0.f, 0.f};
        for (int bch = 0; bch < 4; ++bch) {
            bf16x8 wb[4];
#pragma unroll
            for (int c2 = 0; c2 < 4; ++c2) {
                int k8c = (bch * 4 + c2) * 4 + kq;
                wb[c2] = *(const bf16x8*)(Wm + ((size_t)k8c * 256 + col) * 8);
            }
#pragma unroll
            for (int c2 = 0; c2 < 4; ++c2) {
                int c = bch * 4 + c2;
                bf16x8 af = *(const bf16x8*)(Astage + ((size_t)(c * 4 + kq) * 17 + t16) * 8);
                a0 = MFMA(af, wb[c2], a0);
            }
        }
#pragma unroll
        for (int r = 0; r < 4; ++r) {
            int t8 = __builtin_amdgcn_cvt_pk_fp8_f32(a0[r] * 16.f, 0.f, 0, false);
            regA8[(size_t)(r0 + kq * 4 + r) * OFT + col] = (u8)(t8 & 0xFF);
        }
    }
}

// ============== k2: spmm + q/k GEMM + norm + loss + h-GEMM ==================
// R27 remap: xcd=b&7, bat=xcd>>2, idx=(b>>3)*4+(xcd&3) -> XCD group
// {0-3}=batch0, {4-7}=batch1; per-XCD gather set = one batch (2MB).
__global__ __launch_bounds__(1024, 4) void k2_spmm_qk(
    const u8* __restrict__ regA8, unsigned* __restrict__ KO8,
    ushort_t* __restrict__ regH, const ushort_t* __restrict__ Wp,
    const unsigned* __restrict__ gcols, const int* __restrict__ cnt,
    float* __restrict__ part, float* __restrict__ invnk_g)
{
    __shared__ ushort_t Astage[32 * 17 * 8];
    __shared__ ushort_t csr_c[RPB * CAP];
    __shared__ ushort_t qn_l[RPB * QLS];
    __shared__ float    red[2][RPB][8];
    __shared__ float    dlred[16];

    const int tid = threadIdx.x, wave = tid >> 6, lane = tid & 63;
    const int t16 = lane & 15, kq = lane >> 4, grp = lane >> 4;
    const int b = blockIdx.x;
    const int xcd = b & 7, bat = xcd >> 2;
    const int idx = (b >> 3) * 4 + (xcd & 3);   // row-group within batch
    const int rg  = bat * 256 + idx;            // global row-group
    const int r0  = rg * RPB;
    const size_t batb = (size_t)bat * 4096;

    {
        unsigned* cc = (unsigned*)csr_c;
        if (tid < RPB * CAP / 2) cc[tid] = gcols[rg * (RPB * CAP / 2) + tid];
    }
    __syncthreads();

    // ---- spmm: wave -> row r0+wave
    {
        const int rl = wave;
        const int n = cnt[r0 + rl];
        const u8* gA = regA8 + batb * OFT;
        float a16[16];
#pragma unroll
        for (int j = 0; j < 16; ++j) a16[j] = 0.f;
        const int nIter = (n + 3) >> 2;
        uint4 v;
        {
            int e0 = grp; int val0 = (e0 < n);
            int col0 = csr_c[rl * CAP + (val0 ? e0 : 0)];
            v = *(const uint4*)(gA + (size_t)col0 * OFT + t16 * 16);
        }
        for (int it = 0; it < nIter; ++it) {
            uint4 vn;
            if (it + 1 < nIter) {
                int e1 = (it + 1) * 4 + grp; int val1 = (e1 < n);
                int col1 = csr_c[rl * CAP + (val1 ? e1 : 0)];
                vn = *(const uint4*)(gA + (size_t)col1 * OFT + t16 * 16);
            }
            int e = it * 4 + grp;
            if (e < n) {
                unsigned w4[4] = {v.x, v.y, v.z, v.w};
#pragma unroll
                for (int i2 = 0; i2 < 4; ++i2) {
                    f32x2 x01 = __builtin_amdgcn_cvt_pk_f32_fp8((int)w4[i2], false);
                    f32x2 x23 = __builtin_amdgcn_cvt_pk_f32_fp8((int)w4[i2], true);
                    a16[4*i2+0] += x01.x; a16[4*i2+1] += x01.y;
                    a16[4*i2+2] += x23.x; a16[4*i2+3] += x23.y;
                }
            }
            v = vn;
        }
#pragma unroll
        for (int j = 0; j < 16; ++j) {
            a16[j] += __shfl_xor(a16[j], 16, 64);
            a16[j] += __shfl_xor(a16[j], 32, 64);
        }
        float iv = 1.f / (16.f * (float)max(n, 1));
        float o0 = a16[grp*4+0]*iv, o1 = a16[grp*4+1]*iv;
        float o2 = a16[grp*4+2]*iv, o3 = a16[grp*4+3]*iv;
        int uo = 0;
        uo = __builtin_amdgcn_cvt_pk_fp8_f32(o0*16.f, o1*16.f, uo, false);
        uo = __builtin_amdgcn_cvt_pk_fp8_f32(o2*16.f, o3*16.f, uo, true);
        KO8[(size_t)(r0 + rl) * 64 + (t16 * 4 + grp)] = (unsigned)uo;
        int d0 = t16 * 16 + grp * 4;
        int q8c = d0 >> 3, off = d0 & 7;
        uint2 st; st.x = pack2(o0, o1); st.y = pack2(o2, o3);
        *(uint2*)(Astage + ((size_t)q8c * 17 + rl) * 8 + off) = st;
    }
    __syncthreads();

    // ---- q/k GEMM: waves 0-7 q, 8-15 k; wave -> 32 cols
    const int isK = wave >> 3, w8 = wave & 7;
    const ushort_t* Wm = Wp + (isK ? WP_K : WP_Q);
    f32x4 acc[2];
    acc[0] = (f32x4){0.f,0.f,0.f,0.f};
    acc[1] = (f32x4){0.f,0.f,0.f,0.f};
    for (int bch = 0; bch < 2; ++bch) {
        bf16x8 wb[2][4];
#pragma unroll
        for (int j = 0; j < 2; ++j)
#pragma unroll
            for (int c2 = 0; c2 < 4; ++c2) {
                int col = w8 * 32 + j * 16 + t16;
                int k8c = (bch * 4 + c2) * 4 + kq;
                wb[j][c2] = *(const bf16x8*)(Wm + ((size_t)k8c * 256 + col) * 8);
            }
#pragma unroll
        for (int c2 = 0; c2 < 4; ++c2) {
            int c = bch * 4 + c2;
            bf16x8 af = *(const bf16x8*)(Astage + ((size_t)(c*4 + kq) * 17 + t16) * 8);
            acc[0] = MFMA(af, wb[0][c2], acc[0]);
            acc[1] = MFMA(af, wb[1][c2], acc[1]);
        }
    }
#pragma unroll
    for (int r = 0; r < 4; ++r) {
        float s = acc[0][r]*acc[0][r] + acc[1][r]*acc[1][r];
#pragma unroll
        for (int off = 1; off < 16; off <<= 1) s += __shfl_xor(s, off, 16);
        if (t16 == 0) red[isK][kq*4 + r][w8] = s;
    }
    __syncthreads();
#pragma unroll
    for (int r = 0; r < 4; ++r) {
        int row = kq * 4 + r;
        float s = 0.f;
#pragma unroll
        for (int j = 0; j < 8; ++j) s += red[isK][row][j];
        float inv = 1.f / fmaxf(sqrtf(s), EPSN);
        if (isK && w8 == 0 && t16 == 0) invnk_g[r0 + row] = inv;
#pragma unroll
        for (int j = 0; j < 2; ++j) {
            int col = w8 * 32 + j * 16 + t16;
            float v = acc[j][r] * inv;
            acc[j][r] = v;
            if (!isK) qn_l[row * QLS + col] = f2bf(v);
        }
    }
    __syncthreads();
    if (isK) {
        float dl = 0.f;
#pragma unroll
        for (int r = 0; r < 4; ++r) {
            int row = kq * 4 + r;
#pragma unroll
            for (int j = 0; j < 2; ++j) {
                int col = w8 * 32 + j * 16 + t16;
                float d = bf2f(qn_l[row * QLS + col]) - acc[j][r];
                dl += d * d;
            }
        }
#pragma unroll
        for (int off = 1; off < 64; off <<= 1) dl += __shfl_xor(dl, off, 64);
        if (lane == 0) dlred[wave] = dl;
    }
    __syncthreads();

    // ---- h-GEMM: h[m] = qn[m] . Wk via WP_KT; 16 waves x 16 cols
    {
        const ushort_t* WmT = Wp + WP_KT;
        const int colh = wave * 16 + t16;
        f32x4 h0 = {0.f, 0.f, 0.f, 0.f};
        for (int bch = 0; bch < 2; ++bch) {
            bf16x8 wb[4];
#pragma unroll
            for (int c2 = 0; c2 < 4; ++c2) {
                int k8c = (bch * 4 + c2) * 4 + kq;
                wb[c2] = *(const bf16x8*)(WmT + ((size_t)k8c * 256 + colh) * 8);
            }
#pragma unroll
            for (int c2 = 0; c2 < 4; ++c2) {
                int k8c = (bch * 4 + c2) * 4 + kq;
                bf16x8 af = *(const bf16x8*)(qn_l + (size_t)t16 * QLS + k8c * 8);
                h0 = MFMA(af, wb[c2], h0);
            }
        }
#pragma unroll
        for (int r = 0; r < 4; ++r) {
            int row = kq * 4 + r;
            regH[(size_t)(r0 + row) * OFT + colh] = f2bf(h0[r]);
        }
    }
    if (tid == 0) {
        float s = 0.f;
#pragma unroll
        for (int j = 8; j < 16; ++j) s += dlred[j];
        part[rg] = s;
    }
}

// ============== k3: fused attention + v1 + v2 (16 waves, 16 rows) ===========
// R27 remap: same batch->XCD-group partition as k2.
__global__ __launch_bounds__(1024, 4) void k3_fused(
    const unsigned* __restrict__ KO8, const ushort_t* __restrict__ regH,
    const unsigned* __restrict__ gcols, const int* __restrict__ cnt,
    const ushort_t* __restrict__ Wp, const float* __restrict__ a_v,
    const float* __restrict__ a_act, const float* __restrict__ biasv,
    const float* __restrict__ part, const float* __restrict__ invnk_g,
    float* __restrict__ out)
{
    __shared__ ushort_t csr_c[RPB * CAP];
    __shared__ float    invl[RPB][CAP];
    __shared__ ushort_t Astage[32 * 17 * 8];   // ctx frag layout
    __shared__ ushort_t Hl[32 * 17 * 8];       // h frag layout
    __shared__ float    s8[16];

    const int tid = threadIdx.x, wave = tid >> 6, lane = tid & 63;
    const int t16 = lane & 15, kq = lane >> 4, grp = lane >> 4;
    const int b = blockIdx.x;
    const int xcd = b & 7, bat = xcd >> 2;
    const int idx = (b >> 3) * 4 + (xcd & 3);
    const int rg  = bat * 256 + idx;
    const int r0  = rg * RPB;
    const size_t batb = (size_t)bat * 4096;

    if (b == 0 && tid < 512) {     // div_loss finalize (order-independent sum)
        float s = part[tid];
#pragma unroll
        for (int off = 32; off; off >>= 1) s += __shfl_down(s, off, 64);
        if (lane == 0) s8[wave] = s;
    }
    __syncthreads();
    if (b == 0 && tid == 0) {
        float t = 0.f;
#pragma unroll
        for (int j = 0; j < 8; ++j) t += s8[j];
        out[(size_t)ROWS * OFT] = t * (1.f / 8192.f);
    }

    {
        unsigned* cc = (unsigned*)csr_c;
        if (tid < RPB * CAP / 2) cc[tid] = gcols[rg * (RPB * CAP / 2) + tid];
    }
    __syncthreads();

    // ---- attention: wave -> row; 4 edge slots; 2-deep prefetch
    {
        const int row = r0 + wave;
        const int n = cnt[row];
#pragma unroll
        for (int s = 0; s < 2; ++s) {
            int e = lane + s * 64;
            if (e < n) {
                int col = csr_c[wave * CAP + e];
                invl[wave][e] = invnk_g[batb + col] * 0.0625f;
            }
        }
        float q[16];
        {
            const ushort_t* qp = regH + (size_t)row * OFT + t16 * 16;
            uint4 a = *(const uint4*)qp, bq = *(const uint4*)(qp + 8);
            unsigned uu[8] = {a.x, a.y, a.z, a.w, bq.x, bq.y, bq.z, bq.w};
#pragma unroll
            for (int j = 0; j < 8; ++j) { q[2*j] = lo_f(uu[j]); q[2*j+1] = hi_f(uu[j]); }
        }
        const unsigned* gKO = KO8 + batb * 64;
        float c[16];
#pragma unroll
        for (int j = 0; j < 16; ++j) c[j] = 0.f;
        float sE = 0.f;
        const int nIter = (n + 3) >> 2;
        uint4 v0;
        {
            int e0 = grp; int val0 = (e0 < n);
            int col0 = csr_c[wave * CAP + (val0 ? e0 : 0)];
            v0 = *(const uint4*)(gKO + (size_t)col0 * 64 + t16 * 4);
        }
        for (int it = 0; it < nIter; ++it) {
            uint4 n0;
            if (it + 1 < nIter) {
                int e1 = (it + 1) * 4 + grp; int val1 = (e1 < n);
                int col1 = csr_c[wave * CAP + (val1 ? e1 : 0)];
                n0 = *(const uint4*)(gKO + (size_t)col1 * 64 + t16 * 4);
            }
            int e = it * 4 + grp;
            int valid = (e < n);
            float o[16];
            unsigned w4[4] = {v0.x, v0.y, v0.z, v0.w};
#pragma unroll
            for (int i2 = 0; i2 < 4; ++i2) {
                f32x2 x01 = __builtin_amdgcn_cvt_pk_f32_fp8((int)w4[i2], false);
                f32x2 x23 = __builtin_amdgcn_cvt_pk_f32_fp8((int)w4[i2], true);
                o[4*i2+0] = x01.x; o[4*i2+1] = x01.y;
                o[4*i2+2] = x23.x; o[4*i2+3] = x23.y;
            }
            float d = 0.f;
#pragma unroll
            for (int j = 0; j < 16; ++j) d += q[j] * o[j];
            d = dpp_add<0xB1>(d);    // quad xor1
            d = dpp_add<0x4E>(d);    // quad xor2
            d = dpp_add<0x124>(d);   // row_ror:4
            d = dpp_add<0x128>(d);   // row_ror:8
            float iv16v = invl[wave][valid ? e : 0];
            float es = __expf(d * iv16v);   // unscale outb x16 + k-norm
            es = valid ? es : 0.f;
            sE += es;
#pragma unroll
            for (int j = 0; j < 16; ++j) c[j] += es * o[j];
            v0 = n0;
        }
#pragma unroll
        for (int j = 0; j < 16; ++j) {
            c[j] += __shfl_xor(c[j], 16, 64);
            c[j] += __shfl_xor(c[j], 32, 64);
        }
        sE += __shfl_xor(sE, 16, 64);
        sE += __shfl_xor(sE, 32, 64);
        float inv16 = 0.0625f / sE;          // unscale outb x16 + softmax norm
        {
            int d0 = t16 * 16 + grp * 4;
            int q8c = d0 >> 3, off = d0 & 7;
            uint2 st; st.x = pack2(c[grp*4]*inv16, c[grp*4+1]*inv16);
            st.y = pack2(c[grp*4+2]*inv16, c[grp*4+3]*inv16);
            *(uint2*)(Astage + ((size_t)q8c * 17 + wave) * 8 + off) = st;
        }
    }
    __syncthreads();

    // ---- v1 GEMM + PReLU(a_v) -> Hl
    const int col = wave * 16 + t16;
    {
        const ushort_t* Wm = Wp + WP_V1;
        f32x4 h0 = {0.f,0.f,0.f,0.f};
        for (int bch = 0; bch < 2; ++bch) {
            bf16x8 wb[4];
#pragma unroll
            for (int c2 = 0; c2 < 4; ++c2) {
                int k8c = (bch * 4 + c2) * 4 + kq;
                wb[c2] = *(const bf16x8*)(Wm + ((size_t)k8c * 256 + col) * 8);
            }
#pragma unroll
            for (int c2 = 0; c2 < 4; ++c2) {
                int c = bch * 4 + c2;
                bf16x8 af = *(const bf16x8*)(Astage + ((size_t)(c*4 + kq) * 17 + t16) * 8);
                h0 = MFMA(af, wb[c2], h0);
            }
        }
        float av = *a_v;
        int q8c = col >> 3, off = col & 7;
#pragma unroll
        for (int r = 0; r < 4; ++r) {
            int row = kq * 4 + r;
            float x = h0[r]; x = (x >= 0.f) ? x : av * x;
            Hl[((size_t)q8c * 17 + row) * 8 + off] = f2bf(x);
        }
    }
    __syncthreads();

    // ---- v2 GEMM + bias + PReLU(a_act) -> out (fp32)
    {
        const ushort_t* Wm = Wp + WP_V2;
        f32x4 y0 = {0.f,0.f,0.f,0.f};
        for (int bch = 0; bch < 2; ++bch) {
            bf16x8 wb[4];
#pragma unroll
            for (int c2 = 0; c2 < 4; ++c2) {
                int k8c = (bch * 4 + c2) * 4 + kq;
                wb[c2] = *(const bf16x8*)(Wm + ((size_t)k8c * 256 + col) * 8);
            }
#pragma unroll
            for (int c2 = 0; c2 < 4; ++c2) {
                int c = bch * 4 + c2;
                bf16x8 af = *(const bf16x8*)(Hl + ((size_t)(c*4 + kq) * 17 + t16) * 8);
                y0 = MFMA(af, wb[c2], y0);
            }
        }
        float aa = *a_act;
        float bv = biasv[col];
#pragma unroll
        for (int r = 0; r < 4; ++r) {
            size_t row = (size_t)(r0 + kq * 4 + r);
            float x = y0[r] + bv; x = (x >= 0.f) ? x : aa * x;
            out[row * OFT + col] = x;
        }
    }
}

// ------------------------------------------------------------------- launch
extern "C" void kernel_launch(void* const* d_in, const int* in_sizes, int n_in,
                              void* d_out, int out_size, void* d_ws, size_t ws_size,
                              hipStream_t stream)
{
    const float* seq   = (const float*)d_in[0];
    const float* adj   = (const float*)d_in[1];
    const float* W_fc  = (const float*)d_in[2];
    const float* W_q   = (const float*)d_in[3];
    const float* W_k   = (const float*)d_in[4];
    const float* W_v1  = (const float*)d_in[5];
    const float* W_v2  = (const float*)d_in[6];
    const float* a_v   = (const float*)d_in[7];
    const float* a_act = (const float*)d_in[8];
    const float* bias  = (const float*)d_in[9];

    char* w = (char*)d_ws;
    u8*       regA8 = (u8*)w;                                // seq_fts fp8 2MB
    unsigned* KO8   = (unsigned*)(w + (4u  << 20));          // fp8 outb 2MB
    ushort_t* regH  = (ushort_t*)(w + (12u << 20));          // h=qn.Wk bf16 4MB
    unsigned* gcols = (unsigned*)(w + (16u << 20));          // CSR u16 cols 2MB
    int*      cnt   = (int*)(w + (20u << 20));               // 32KB
    float*    part  = (float*)(w + (20u << 20) + 32768);     // 2KB
    float*    invnk = (float*)(w + (20u << 20) + 65536);     // 32KB
    ushort_t* Wp    = (ushort_t*)(w + (21u << 20));          // 896KB frag weights

    k0_prep<<<224, 256, 0, stream>>>(W_fc, W_q, W_k, W_v1, W_v2, Wp);
    k1_extract_fc<<<NBLK, 1024, 0, stream>>>(seq, adj, Wp, regA8, gcols, cnt);
    k2_spmm_qk<<<NBLK, 1024, 0, stream>>>(regA8, KO8, regH, Wp, gcols, cnt,
                                          part, invnk);
    k3_fused<<<NBLK, 1024, 0, stream>>>(KO8, regH, gcols, cnt, Wp,
                                        a_v, a_act, bias, part, invnk,
                                        (float*)d_out);
}

// Round 10
// 275.048 us; speedup vs baseline: 1.8456x; 1.0017x over previous
//
#include <hip/hip_runtime.h>
#include <hip/hip_bf16.h>

// GCN attention forward, MI355X. fp32 inputs (counter-proven R14).
// R25 counters: k2/k3 gathers miss L2 persistently (FETCH 64.5MB/rep vs
// 2-4MB working set), effective ~2.5TB/s fabric rate. R26 dim-slice
// FAILED (+16, structural overhead). R27 blockIdx%8 batch->XCD remap
// NULL (+0.8) -> mapping guess unreliable.
// R28: per-XCD REPLICAS of KO8 (k3's gather buffer), reader picks copy
// by the HARDWARE XCC id (s_getreg hwreg(HW_REG_XCC_ID), m09-verified).
// k2 writes all 8 copies (8 contiguous dword stores, ~1us); k3 gathers
// from its own XCD's copy -> only compulsory L2 misses, 42x line reuse.
// Correctness is mapping-independent (all copies identical). regA8 (k2)
// not replicated yet: 4MB copy > L2; ported next if this WINs.
// k0 Wprep(+WkT) | k1 extract+fc(fp8) | k2 spmm+qk+h | k3 attn+v1+v2.

#define NN    4096
#define ROWS  8192
#define OFT   256
#define CAP   128
#define NBLK  512
#define RPB   16
#define QLS   264   // qn_l row stride (ushort) — bank-spread for h-GEMM reads
#define KCPY  524288u   // dwords per KO8 replica (8192 rows x 64)
#define EPSN  1e-12f
#define MFMA(a,b,c) __builtin_amdgcn_mfma_f32_16x16x32_bf16((a),(b),(c),0,0,0)

typedef unsigned short ushort_t;
typedef unsigned char  u8;
typedef __attribute__((ext_vector_type(8))) short bf16x8;
typedef __attribute__((ext_vector_type(4))) float f32x4;
typedef __attribute__((ext_vector_type(2))) float f32x2;

#define WP_FC   0
#define WP_Q    (16384 * 8)
#define WP_K    (WP_Q + 8192 * 8)
#define WP_V1   (WP_K + 8192 * 8)
#define WP_V2   (WP_V1 + 8192 * 8)
#define WP_KT   (WP_V2 + 8192 * 8)   // Wk transposed frags: [p-kmajor][o-col]

__device__ __forceinline__ float lo_f(unsigned u) { union { unsigned i; float f; } c; c.i = u << 16;          return c.f; }
__device__ __forceinline__ float hi_f(unsigned u) { union { unsigned i; float f; } c; c.i = u & 0xFFFF0000u;  return c.f; }
__device__ __forceinline__ float bf2f(ushort_t u) { union { unsigned i; float f; } c; c.i = (unsigned)u << 16; return c.f; }
__device__ __forceinline__ ushort_t f2bf(float f) {
    union { float f; unsigned i; } c; c.f = f;
    unsigned r = c.i + 0x7FFFu + ((c.i >> 16) & 1u);
    return (ushort_t)(r >> 16);
}
__device__ __forceinline__ unsigned pack2(float a, float b) {
    return (unsigned)f2bf(a) | ((unsigned)f2bf(b) << 16);
}

template<int CTRL>
__device__ __forceinline__ float dpp_add(float x) {
    union { float f; int i; } c; c.f = x;
    int y = __builtin_amdgcn_update_dpp(c.i, c.i, CTRL, 0xF, 0xF, false);
    union { int i; float f; } r; r.i = y;
    return x + r.f;
}

// ===================== k0: weight prep -> bf16 frag layout ==================
__global__ __launch_bounds__(256) void k0_prep(
    const float* __restrict__ Wfc, const float* __restrict__ Wq,
    const float* __restrict__ Wk,  const float* __restrict__ Wv1,
    const float* __restrict__ Wv2, ushort_t* __restrict__ Wp)
{
    int sid = blockIdx.x * 256 + threadIdx.x;
    if (sid >= 49152) {            // WkT: frag (p8, col=o): Wk[p8*8+i][o]
        int t = sid - 49152;       // 0..8191
        int o = t & 255, p8 = t >> 8;
        ushort_t tmp[8];
#pragma unroll
        for (int i = 0; i < 8; ++i)
            tmp[i] = f2bf(Wk[(size_t)(p8 * 8 + i) * 256 + o]);
        *(bf16x8*)(Wp + WP_KT + (size_t)t * 8) = *(bf16x8*)tmp;
        return;
    }
    const float* src; int K, local; ushort_t* dst;
    if (sid < 16384) { src = Wfc; K = 512; local = sid; dst = Wp + WP_FC + (size_t)local * 8; }
    else {
        int s = sid - 16384, which = s >> 13; local = s & 8191;
        const float* ws4[4] = {Wq, Wk, Wv1, Wv2};
        src = ws4[which]; K = 256;
        dst = Wp + WP_Q + (size_t)which * 65536 + (size_t)local * 8;
    }
    int col = local & 255, k8c = local >> 8;
    const float* p = src + (size_t)col * K + k8c * 8;
    float4 x0 = *(const float4*)p, x1 = *(const float4*)(p + 4);
    uint4 o; o.x = pack2(x0.x, x0.y); o.y = pack2(x0.z, x0.w);
    o.z = pack2(x1.x, x1.y); o.w = pack2(x1.z, x1.w);
    *(uint4*)dst = o;
}

// ============================ k1: extract + fc ==============================
__global__ __launch_bounds__(1024, 4) void k1_extract_fc(
    const float* __restrict__ seq, const float* __restrict__ adj,
    const ushort_t* __restrict__ Wp, u8* __restrict__ regA8,
    unsigned* __restrict__ gcols, int* __restrict__ cnt)
{
    __shared__ ushort_t Astage[64 * 17 * 8];
    __shared__ ushort_t csr_c[RPB * CAP];
    __shared__ int      csr_n[RPB];

    const int tid = threadIdx.x, wave = tid >> 6, lane = tid & 63;
    const int t16 = lane & 15, kq = lane >> 4;
    const int b = blockIdx.x, r0 = b * RPB;

    {   // extract: wave -> row; all 16 float4 loads up-front
        const float4* rowp = (const float4*)(adj + (size_t)(r0 + wave) * NN);
        float4 v[16];
#pragma unroll
        for (int t = 0; t < 16; ++t) v[t] = rowp[t * 64 + lane];
        int base = 0;
#pragma unroll
        for (int h = 0; h < 2; ++h) {
            int c = 0;
#pragma unroll
            for (int t = 0; t < 8; ++t) {
                const float4& x = v[h * 8 + t];
                c += (x.x > 0.f) + (x.y > 0.f) + (x.z > 0.f) + (x.w > 0.f);
            }
            int incl = c;
#pragma unroll
            for (int off = 1; off < 64; off <<= 1) {
                int y = __shfl_up(incl, off, 64);
                if (lane >= off) incl += y;
            }
            int p = base + incl - c;
            base += __shfl(incl, 63, 64);
#pragma unroll
            for (int t = 0; t < 8; ++t) {
                const float4& x = v[h * 8 + t];
                float f[4] = {x.x, x.y, x.z, x.w};
#pragma unroll
                for (int j = 0; j < 4; ++j)
                    if (f[j] > 0.f) {
                        if (p < CAP)
                            csr_c[wave * CAP + p] = (ushort_t)(((h * 8 + t) * 64 + lane) * 4 + j);
                        ++p;
                    }
            }
        }
        if (lane == 0) csr_n[wave] = (base < CAP) ? base : CAP;
    }
    __syncthreads();
    {
        const unsigned* cc = (const unsigned*)csr_c;
        if (tid < RPB * CAP / 2) gcols[b * (RPB * CAP / 2) + tid] = cc[tid];
        if (tid < RPB) cnt[r0 + tid] = csr_n[tid];
    }

    // ---- stage seq 16 x 512 (fp32 -> bf16, k-major frag layout)
    {
        int row = tid >> 6, seg = tid & 63;
        const float* p = seq + (size_t)(r0 + row) * 512 + seg * 8;
        float4 x0 = *(const float4*)p, x1 = *(const float4*)(p + 4);
        uint4 a;
        a.x = pack2(x0.x, x0.y); a.y = pack2(x0.z, x0.w);
        a.z = pack2(x1.x, x1.y); a.w = pack2(x1.z, x1.w);
        *(bf16x8*)(Astage + ((size_t)seg * 17 + row) * 8) = *(bf16x8*)&a;
    }
    __syncthreads();

    // ---- fc GEMM: wave -> 16 cols; epilogue -> fp8 x16 byte stores
    {
        const int col = wave * 16 + t16;
        const ushort_t* Wm = Wp + WP_FC;
        f32x4 a0 = {0.f, 0.f, 0.f, 0.f};
        for (int bch = 0; bch < 4; ++bch) {
            bf16x8 wb[4];
#pragma unroll
            for (int c2 = 0; c2 < 4; ++c2) {
                int k8c = (bch * 4 + c2) * 4 + kq;
                wb[c2] = *(const bf16x8*)(Wm + ((size_t)k8c * 256 + col) * 8);
            }
#pragma unroll
            for (int c2 = 0; c2 < 4; ++c2) {
                int c = bch * 4 + c2;
                bf16x8 af = *(const bf16x8*)(Astage + ((size_t)(c * 4 + kq) * 17 + t16) * 8);
                a0 = MFMA(af, wb[c2], a0);
            }
        }
#pragma unroll
        for (int r = 0; r < 4; ++r) {
            int t8 = __builtin_amdgcn_cvt_pk_fp8_f32(a0[r] * 16.f, 0.f, 0, false);
            regA8[(size_t)(r0 + kq * 4 + r) * OFT + col] = (u8)(t8 & 0xFF);
        }
    }
}

// ============== k2: spmm + q/k GEMM + norm + loss + h-GEMM ==================
// R27 remap kept (harmless, confines each XCD's rows to one batch).
// R28: KO8 written to 8 per-XCD replicas (KO8R).
__global__ __launch_bounds__(1024, 4) void k2_spmm_qk(
    const u8* __restrict__ regA8, unsigned* __restrict__ KO8R,
    ushort_t* __restrict__ regH, const ushort_t* __restrict__ Wp,
    const unsigned* __restrict__ gcols, const int* __restrict__ cnt,
    float* __restrict__ part, float* __restrict__ invnk_g)
{
    __shared__ ushort_t Astage[32 * 17 * 8];
    __shared__ ushort_t csr_c[RPB * CAP];
    __shared__ ushort_t qn_l[RPB * QLS];
    __shared__ float    red[2][RPB][8];
    __shared__ float    dlred[16];

    const int tid = threadIdx.x, wave = tid >> 6, lane = tid & 63;
    const int t16 = lane & 15, kq = lane >> 4, grp = lane >> 4;
    const int b = blockIdx.x;
    const int xcd = b & 7, bat = xcd >> 2;
    const int idx = (b >> 3) * 4 + (xcd & 3);   // row-group within batch
    const int rg  = bat * 256 + idx;            // global row-group
    const int r0  = rg * RPB;
    const size_t batb = (size_t)bat * 4096;

    {
        unsigned* cc = (unsigned*)csr_c;
        if (tid < RPB * CAP / 2) cc[tid] = gcols[rg * (RPB * CAP / 2) + tid];
    }
    __syncthreads();

    // ---- spmm: wave -> row r0+wave
    {
        const int rl = wave;
        const int n = cnt[r0 + rl];
        const u8* gA = regA8 + batb * OFT;
        float a16[16];
#pragma unroll
        for (int j = 0; j < 16; ++j) a16[j] = 0.f;
        const int nIter = (n + 3) >> 2;
        uint4 v;
        {
            int e0 = grp; int val0 = (e0 < n);
            int col0 = csr_c[rl * CAP + (val0 ? e0 : 0)];
            v = *(const uint4*)(gA + (size_t)col0 * OFT + t16 * 16);
        }
        for (int it = 0; it < nIter; ++it) {
            uint4 vn;
            if (it + 1 < nIter) {
                int e1 = (it + 1) * 4 + grp; int val1 = (e1 < n);
                int col1 = csr_c[rl * CAP + (val1 ? e1 : 0)];
                vn = *(const uint4*)(gA + (size_t)col1 * OFT + t16 * 16);
            }
            int e = it * 4 + grp;
            if (e < n) {
                unsigned w4[4] = {v.x, v.y, v.z, v.w};
#pragma unroll
                for (int i2 = 0; i2 < 4; ++i2) {
                    f32x2 x01 = __builtin_amdgcn_cvt_pk_f32_fp8((int)w4[i2], false);
                    f32x2 x23 = __builtin_amdgcn_cvt_pk_f32_fp8((int)w4[i2], true);
                    a16[4*i2+0] += x01.x; a16[4*i2+1] += x01.y;
                    a16[4*i2+2] += x23.x; a16[4*i2+3] += x23.y;
                }
            }
            v = vn;
        }
#pragma unroll
        for (int j = 0; j < 16; ++j) {
            a16[j] += __shfl_xor(a16[j], 16, 64);
            a16[j] += __shfl_xor(a16[j], 32, 64);
        }
        float iv = 1.f / (16.f * (float)max(n, 1));
        float o0 = a16[grp*4+0]*iv, o1 = a16[grp*4+1]*iv;
        float o2 = a16[grp*4+2]*iv, o3 = a16[grp*4+3]*iv;
        int uo = 0;
        uo = __builtin_amdgcn_cvt_pk_fp8_f32(o0*16.f, o1*16.f, uo, false);
        uo = __builtin_amdgcn_cvt_pk_fp8_f32(o2*16.f, o3*16.f, uo, true);
        {   // R28: write all 8 per-XCD replicas (identical data)
            size_t base = (size_t)(r0 + rl) * 64 + (t16 * 4 + grp);
#pragma unroll
            for (int cpy = 0; cpy < 8; ++cpy)
                KO8R[(size_t)cpy * KCPY + base] = (unsigned)uo;
        }
        int d0 = t16 * 16 + grp * 4;
        int q8c = d0 >> 3, off = d0 & 7;
        uint2 st; st.x = pack2(o0, o1); st.y = pack2(o2, o3);
        *(uint2*)(Astage + ((size_t)q8c * 17 + rl) * 8 + off) = st;
    }
    __syncthreads();

    // ---- q/k GEMM: waves 0-7 q, 8-15 k; wave -> 32 cols
    const int isK = wave >> 3, w8 = wave & 7;
    const ushort_t* Wm = Wp + (isK ? WP_K : WP_Q);
    f32x4 acc[2];
    acc[0] = (f32x4){0.f,0.f,0.f,0.f};
    acc[1] = (f32x4){0.f,0.f,0.f,0.f};
    for (int bch = 0; bch < 2; ++bch) {
        bf16x8 wb[2][4];
#pragma unroll
        for (int j = 0; j < 2; ++j)
#pragma unroll
            for (int c2 = 0; c2 < 4; ++c2) {
                int col = w8 * 32 + j * 16 + t16;
                int k8c = (bch * 4 + c2) * 4 + kq;
                wb[j][c2] = *(const bf16x8*)(Wm + ((size_t)k8c * 256 + col) * 8);
            }
#pragma unroll
        for (int c2 = 0; c2 < 4; ++c2) {
            int c = bch * 4 + c2;
            bf16x8 af = *(const bf16x8*)(Astage + ((size_t)(c*4 + kq) * 17 + t16) * 8);
            acc[0] = MFMA(af, wb[0][c2], acc[0]);
            acc[1] = MFMA(af, wb[1][c2], acc[1]);
        }
    }
#pragma unroll
    for (int r = 0; r < 4; ++r) {
        float s = acc[0][r]*acc[0][r] + acc[1][r]*acc[1][r];
#pragma unroll
        for (int off = 1; off < 16; off <<= 1) s += __shfl_xor(s, off, 16);
        if (t16 == 0) red[isK][kq*4 + r][w8] = s;
    }
    __syncthreads();
#pragma unroll
    for (int r = 0; r < 4; ++r) {
        int row = kq * 4 + r;
        float s = 0.f;
#pragma unroll
        for (int j = 0; j < 8; ++j) s += red[isK][row][j];
        float inv = 1.f / fmaxf(sqrtf(s), EPSN);
        if (isK && w8 == 0 && t16 == 0) invnk_g[r0 + row] = inv;
#pragma unroll
        for (int j = 0; j < 2; ++j) {
            int col = w8 * 32 + j * 16 + t16;
            float v = acc[j][r] * inv;
            acc[j][r] = v;
            if (!isK) qn_l[row * QLS + col] = f2bf(v);
        }
    }
    __syncthreads();
    if (isK) {
        float dl = 0.f;
#pragma unroll
        for (int r = 0; r < 4; ++r) {
            int row = kq * 4 + r;
#pragma unroll
            for (int j = 0; j < 2; ++j) {
                int col = w8 * 32 + j * 16 + t16;
                float d = bf2f(qn_l[row * QLS + col]) - acc[j][r];
                dl += d * d;
            }
        }
#pragma unroll
        for (int off = 1; off < 64; off <<= 1) dl += __shfl_xor(dl, off, 64);
        if (lane == 0) dlred[wave] = dl;
    }
    __syncthreads();

    // ---- h-GEMM: h[m] = qn[m] . Wk via WP_KT; 16 waves x 16 cols
    {
        const ushort_t* WmT = Wp + WP_KT;
        const int colh = wave * 16 + t16;
        f32x4 h0 = {0.f, 0.f, 0.f, 0.f};
        for (int bch = 0; bch < 2; ++bch) {
            bf16x8 wb[4];
#pragma unroll
            for (int c2 = 0; c2 < 4; ++c2) {
                int k8c = (bch * 4 + c2) * 4 + kq;
                wb[c2] = *(const bf16x8*)(WmT + ((size_t)k8c * 256 + colh) * 8);
            }
#pragma unroll
            for (int c2 = 0; c2 < 4; ++c2) {
                int k8c = (bch * 4 + c2) * 4 + kq;
                bf16x8 af = *(const bf16x8*)(qn_l + (size_t)t16 * QLS + k8c * 8);
                h0 = MFMA(af, wb[c2], h0);
            }
        }
#pragma unroll
        for (int r = 0; r < 4; ++r) {
            int row = kq * 4 + r;
            regH[(size_t)(r0 + row) * OFT + colh] = f2bf(h0[r]);
        }
    }
    if (tid == 0) {
        float s = 0.f;
#pragma unroll
        for (int j = 8; j < 16; ++j) s += dlred[j];
        part[rg] = s;
    }
}

// ============== k3: fused attention + v1 + v2 (16 waves, 16 rows) ===========
// R28: gather from the replica owned by THIS XCD (hardware XCC id).
__global__ __launch_bounds__(1024, 4) void k3_fused(
    const unsigned* __restrict__ KO8R, const ushort_t* __restrict__ regH,
    const unsigned* __restrict__ gcols, const int* __restrict__ cnt,
    const ushort_t* __restrict__ Wp, const float* __restrict__ a_v,
    const float* __restrict__ a_act, const float* __restrict__ biasv,
    const float* __restrict__ part, const float* __restrict__ invnk_g,
    float* __restrict__ out)
{
    __shared__ ushort_t csr_c[RPB * CAP];
    __shared__ float    invl[RPB][CAP];
    __shared__ ushort_t Astage[32 * 17 * 8];   // ctx frag layout
    __shared__ ushort_t Hl[32 * 17 * 8];       // h frag layout
    __shared__ float    s8[16];

    const int tid = threadIdx.x, wave = tid >> 6, lane = tid & 63;
    const int t16 = lane & 15, kq = lane >> 4, grp = lane >> 4;
    const int b = blockIdx.x;
    const int xcd = b & 7, bat = xcd >> 2;
    const int idx = (b >> 3) * 4 + (xcd & 3);
    const int rg  = bat * 256 + idx;
    const int r0  = rg * RPB;
    const size_t batb = (size_t)bat * 4096;

    // R28: physical XCD id (wave-uniform; any value 0-7 is CORRECT since
    // all replicas are identical — only locality depends on it).
    unsigned xcc;
    asm volatile("s_getreg_b32 %0, hwreg(HW_REG_XCC_ID)" : "=s"(xcc));
    xcc &= 7u;

    if (b == 0 && tid < 512) {     // div_loss finalize (order-independent sum)
        float s = part[tid];
#pragma unroll
        for (int off = 32; off; off >>= 1) s += __shfl_down(s, off, 64);
        if (lane == 0) s8[wave] = s;
    }
    __syncthreads();
    if (b == 0 && tid == 0) {
        float t = 0.f;
#pragma unroll
        for (int j = 0; j < 8; ++j) t += s8[j];
        out[(size_t)ROWS * OFT] = t * (1.f / 8192.f);
    }

    {
        unsigned* cc = (unsigned*)csr_c;
        if (tid < RPB * CAP / 2) cc[tid] = gcols[rg * (RPB * CAP / 2) + tid];
    }
    __syncthreads();

    // ---- attention: wave -> row; 4 edge slots; 2-deep prefetch
    {
        const int row = r0 + wave;
        const int n = cnt[row];
#pragma unroll
        for (int s = 0; s < 2; ++s) {
            int e = lane + s * 64;
            if (e < n) {
                int col = csr_c[wave * CAP + e];
                invl[wave][e] = invnk_g[batb + col] * 0.0625f;
            }
        }
        float q[16];
        {
            const ushort_t* qp = regH + (size_t)row * OFT + t16 * 16;
            uint4 a = *(const uint4*)qp, bq = *(const uint4*)(qp + 8);
            unsigned uu[8] = {a.x, a.y, a.z, a.w, bq.x, bq.y, bq.z, bq.w};
#pragma unroll
            for (int j = 0; j < 8; ++j) { q[2*j] = lo_f(uu[j]); q[2*j+1] = hi_f(uu[j]); }
        }
        const unsigned* gKO = KO8R + (size_t)xcc * KCPY + batb * 64;
        float c[16];
#pragma unroll
        for (int j = 0; j < 16; ++j) c[j] = 0.f;
        float sE = 0.f;
        const int nIter = (n + 3) >> 2;
        uint4 v0;
        {
            int e0 = grp; int val0 = (e0 < n);
            int col0 = csr_c[wave * CAP + (val0 ? e0 : 0)];
            v0 = *(const uint4*)(gKO + (size_t)col0 * 64 + t16 * 4);
        }
        for (int it = 0; it < nIter; ++it) {
            uint4 n0;
            if (it + 1 < nIter) {
                int e1 = (it + 1) * 4 + grp; int val1 = (e1 < n);
                int col1 = csr_c[wave * CAP + (val1 ? e1 : 0)];
                n0 = *(const uint4*)(gKO + (size_t)col1 * 64 + t16 * 4);
            }
            int e = it * 4 + grp;
            int valid = (e < n);
            float o[16];
            unsigned w4[4] = {v0.x, v0.y, v0.z, v0.w};
#pragma unroll
            for (int i2 = 0; i2 < 4; ++i2) {
                f32x2 x01 = __builtin_amdgcn_cvt_pk_f32_fp8((int)w4[i2], false);
                f32x2 x23 = __builtin_amdgcn_cvt_pk_f32_fp8((int)w4[i2], true);
                o[4*i2+0] = x01.x; o[4*i2+1] = x01.y;
                o[4*i2+2] = x23.x; o[4*i2+3] = x23.y;
            }
            float d = 0.f;
#pragma unroll
            for (int j = 0; j < 16; ++j) d += q[j] * o[j];
            d = dpp_add<0xB1>(d);    // quad xor1
            d = dpp_add<0x4E>(d);    // quad xor2
            d = dpp_add<0x124>(d);   // row_ror:4
            d = dpp_add<0x128>(d);   // row_ror:8
            float iv16v = invl[wave][valid ? e : 0];
            float es = __expf(d * iv16v);   // unscale outb x16 + k-norm
            es = valid ? es : 0.f;
            sE += es;
#pragma unroll
            for (int j = 0; j < 16; ++j) c[j] += es * o[j];
            v0 = n0;
        }
#pragma unroll
        for (int j = 0; j < 16; ++j) {
            c[j] += __shfl_xor(c[j], 16, 64);
            c[j] += __shfl_xor(c[j], 32, 64);
        }
        sE += __shfl_xor(sE, 16, 64);
        sE += __shfl_xor(sE, 32, 64);
        float inv16 = 0.0625f / sE;          // unscale outb x16 + softmax norm
        {
            int d0 = t16 * 16 + grp * 4;
            int q8c = d0 >> 3, off = d0 & 7;
            uint2 st; st.x = pack2(c[grp*4]*inv16, c[grp*4+1]*inv16);
            st.y = pack2(c[grp*4+2]*inv16, c[grp*4+3]*inv16);
            *(uint2*)(Astage + ((size_t)q8c * 17 + wave) * 8 + off) = st;
        }
    }
    __syncthreads();

    // ---- v1 GEMM + PReLU(a_v) -> Hl
    const int col = wave * 16 + t16;
    {
        const ushort_t* Wm = Wp + WP_V1;
        f32x4 h0 = {0.f,0.f,0.f,0.f};
        for (int bch = 0; bch < 2; ++bch) {
            bf16x8 wb[4];
#pragma unroll
            for (int c2 = 0; c2 < 4; ++c2) {
                int k8c = (bch * 4 + c2) * 4 + kq;
                wb[c2] = *(const bf16x8*)(Wm + ((size_t)k8c * 256 + col) * 8);
            }
#pragma unroll
            for (int c2 = 0; c2 < 4; ++c2) {
                int c = bch * 4 + c2;
                bf16x8 af = *(const bf16x8*)(Astage + ((size_t)(c*4 + kq) * 17 + t16) * 8);
                h0 = MFMA(af, wb[c2], h0);
            }
        }
        float av = *a_v;
        int q8c = col >> 3, off = col & 7;
#pragma unroll
        for (int r = 0; r < 4; ++r) {
            int row = kq * 4 + r;
            float x = h0[r]; x = (x >= 0.f) ? x : av * x;
            Hl[((size_t)q8c * 17 + row) * 8 + off] = f2bf(x);
        }
    }
    __syncthreads();

    // ---- v2 GEMM + bias + PReLU(a_act) -> out (fp32)
    {
        const ushort_t* Wm = Wp + WP_V2;
        f32x4 y0 = {0.f,0.f,0.f,0.f};
        for (int bch = 0; bch < 2; ++bch) {
            bf16x8 wb[4];
#pragma unroll
            for (int c2 = 0; c2 < 4; ++c2) {
                int k8c = (bch * 4 + c2) * 4 + kq;
                wb[c2] = *(const bf16x8*)(Wm + ((size_t)k8c * 256 + col) * 8);
            }
#pragma unroll
            for (int c2 = 0; c2 < 4; ++c2) {
                int c = bch * 4 + c2;
                bf16x8 af = *(const bf16x8*)(Hl + ((size_t)(c*4 + kq) * 17 + t16) * 8);
                y0 = MFMA(af, wb[c2], y0);
            }
        }
        float aa = *a_act;
        float bv = biasv[col];
#pragma unroll
        for (int r = 0; r < 4; ++r) {
            size_t row = (size_t)(r0 + kq * 4 + r);
            float x = y0[r] + bv; x = (x >= 0.f) ? x : aa * x;
            out[row * OFT + col] = x;
        }
    }
}

// ------------------------------------------------------------------- launch
extern "C" void kernel_launch(void* const* d_in, const int* in_sizes, int n_in,
                              void* d_out, int out_size, void* d_ws, size_t ws_size,
                              hipStream_t stream)
{
    const float* seq   = (const float*)d_in[0];
    const float* adj   = (const float*)d_in[1];
    const float* W_fc  = (const float*)d_in[2];
    const float* W_q   = (const float*)d_in[3];
    const float* W_k   = (const float*)d_in[4];
    const float* W_v1  = (const float*)d_in[5];
    const float* W_v2  = (const float*)d_in[6];
    const float* a_v   = (const float*)d_in[7];
    const float* a_act = (const float*)d_in[8];
    const float* bias  = (const float*)d_in[9];

    char* w = (char*)d_ws;
    u8*       regA8 = (u8*)w;                                // seq_fts fp8 2MB
    ushort_t* regH  = (ushort_t*)(w + (12u << 20));          // h=qn.Wk bf16 4MB
    unsigned* gcols = (unsigned*)(w + (16u << 20));          // CSR u16 cols 2MB
    int*      cnt   = (int*)(w + (20u << 20));               // 32KB
    float*    part  = (float*)(w + (20u << 20) + 32768);     // 2KB
    float*    invnk = (float*)(w + (20u << 20) + 65536);     // 32KB
    ushort_t* Wp    = (ushort_t*)(w + (21u << 20));          // 896KB frag weights
    unsigned* KO8R  = (unsigned*)(w + (32u << 20));          // 8 x 2MB replicas

    k0_prep<<<224, 256, 0, stream>>>(W_fc, W_q, W_k, W_v1, W_v2, Wp);
    k1_extract_fc<<<NBLK, 1024, 0, stream>>>(seq, adj, Wp, regA8, gcols, cnt);
    k2_spmm_qk<<<NBLK, 1024, 0, stream>>>(regA8, KO8R, regH, Wp, gcols, cnt,
                                          part, invnk);
    k3_fused<<<NBLK, 1024, 0, stream>>>(KO8R, regH, gcols, cnt, Wp,
                                        a_v, a_act, bias, part, invnk,
                                        (float*)d_out);
}

// Round 11
// 274.500 us; speedup vs baseline: 1.8492x; 1.0020x over previous
//
#include <hip/hip_runtime.h>
#include <hip/hip_bf16.h>

// GCN attention forward, MI355X. fp32 inputs (counter-proven R14).
// FINAL (R29 = exact R22, the measured best 274.7us).
// Window accounting: ~200us harness fills/restore (83-87% HBM peak, at
// roofline) + ~76us kernels: k0~2, k1~22 (adj 134MB HBM floor), k2~28,
// k3~25. k2/k3 falsification record (7 mechanisms, all null/negative):
// request-rate (R22 -1.6), bytes (R18 null), pipelining (R20 +4.5),
// nt-store L2 bypass (R24 +10.5), dim-slice (R26 +16), blockIdx->XCD
// remap (R27 null), HW-XCC_ID per-XCD replicas (R28 null). R25 PMC:
// VALU 26% / Mfma 3% / Occ 45% / FETCH ~= logical gather volume ->
// random 256B-granule gather latency/fabric wall (~2.5TB/s), invariant
// under source-level transformation. Remaining ideas are <=2% EV.
// k0 Wprep(+WkT) | k1 extract+fc(fp8) | k2 spmm+qk+h | k3 attn+v1+v2.

#define NN    4096
#define ROWS  8192
#define OFT   256
#define CAP   128
#define NBLK  512
#define RPB   16
#define QLS   264   // qn_l row stride (ushort) — bank-spread for h-GEMM reads
#define EPSN  1e-12f
#define MFMA(a,b,c) __builtin_amdgcn_mfma_f32_16x16x32_bf16((a),(b),(c),0,0,0)

typedef unsigned short ushort_t;
typedef unsigned char  u8;
typedef __attribute__((ext_vector_type(8))) short bf16x8;
typedef __attribute__((ext_vector_type(4))) float f32x4;
typedef __attribute__((ext_vector_type(2))) float f32x2;

#define WP_FC   0
#define WP_Q    (16384 * 8)
#define WP_K    (WP_Q + 8192 * 8)
#define WP_V1   (WP_K + 8192 * 8)
#define WP_V2   (WP_V1 + 8192 * 8)
#define WP_KT   (WP_V2 + 8192 * 8)   // Wk transposed frags: [p-kmajor][o-col]

__device__ __forceinline__ float lo_f(unsigned u) { union { unsigned i; float f; } c; c.i = u << 16;          return c.f; }
__device__ __forceinline__ float hi_f(unsigned u) { union { unsigned i; float f; } c; c.i = u & 0xFFFF0000u;  return c.f; }
__device__ __forceinline__ float bf2f(ushort_t u) { union { unsigned i; float f; } c; c.i = (unsigned)u << 16; return c.f; }
__device__ __forceinline__ ushort_t f2bf(float f) {
    union { float f; unsigned i; } c; c.f = f;
    unsigned r = c.i + 0x7FFFu + ((c.i >> 16) & 1u);
    return (ushort_t)(r >> 16);
}
__device__ __forceinline__ unsigned pack2(float a, float b) {
    return (unsigned)f2bf(a) | ((unsigned)f2bf(b) << 16);
}

template<int CTRL>
__device__ __forceinline__ float dpp_add(float x) {
    union { float f; int i; } c; c.f = x;
    int y = __builtin_amdgcn_update_dpp(c.i, c.i, CTRL, 0xF, 0xF, false);
    union { int i; float f; } r; r.i = y;
    return x + r.f;
}

// ===================== k0: weight prep -> bf16 frag layout ==================
__global__ __launch_bounds__(256) void k0_prep(
    const float* __restrict__ Wfc, const float* __restrict__ Wq,
    const float* __restrict__ Wk,  const float* __restrict__ Wv1,
    const float* __restrict__ Wv2, ushort_t* __restrict__ Wp)
{
    int sid = blockIdx.x * 256 + threadIdx.x;
    if (sid >= 49152) {            // WkT: frag (p8, col=o): Wk[p8*8+i][o]
        int t = sid - 49152;       // 0..8191
        int o = t & 255, p8 = t >> 8;
        ushort_t tmp[8];
#pragma unroll
        for (int i = 0; i < 8; ++i)
            tmp[i] = f2bf(Wk[(size_t)(p8 * 8 + i) * 256 + o]);
        *(bf16x8*)(Wp + WP_KT + (size_t)t * 8) = *(bf16x8*)tmp;
        return;
    }
    const float* src; int K, local; ushort_t* dst;
    if (sid < 16384) { src = Wfc; K = 512; local = sid; dst = Wp + WP_FC + (size_t)local * 8; }
    else {
        int s = sid - 16384, which = s >> 13; local = s & 8191;
        const float* ws4[4] = {Wq, Wk, Wv1, Wv2};
        src = ws4[which]; K = 256;
        dst = Wp + WP_Q + (size_t)which * 65536 + (size_t)local * 8;
    }
    int col = local & 255, k8c = local >> 8;
    const float* p = src + (size_t)col * K + k8c * 8;
    float4 x0 = *(const float4*)p, x1 = *(const float4*)(p + 4);
    uint4 o; o.x = pack2(x0.x, x0.y); o.y = pack2(x0.z, x0.w);
    o.z = pack2(x1.x, x1.y); o.w = pack2(x1.z, x1.w);
    *(uint4*)dst = o;
}

// ============================ k1: extract + fc ==============================
__global__ __launch_bounds__(1024, 4) void k1_extract_fc(
    const float* __restrict__ seq, const float* __restrict__ adj,
    const ushort_t* __restrict__ Wp, u8* __restrict__ regA8,
    unsigned* __restrict__ gcols, int* __restrict__ cnt)
{
    __shared__ ushort_t Astage[64 * 17 * 8];
    __shared__ ushort_t csr_c[RPB * CAP];
    __shared__ int      csr_n[RPB];

    const int tid = threadIdx.x, wave = tid >> 6, lane = tid & 63;
    const int t16 = lane & 15, kq = lane >> 4;
    const int b = blockIdx.x, r0 = b * RPB;

    {   // extract: wave -> row; all 16 float4 loads up-front
        const float4* rowp = (const float4*)(adj + (size_t)(r0 + wave) * NN);
        float4 v[16];
#pragma unroll
        for (int t = 0; t < 16; ++t) v[t] = rowp[t * 64 + lane];
        int base = 0;
#pragma unroll
        for (int h = 0; h < 2; ++h) {
            int c = 0;
#pragma unroll
            for (int t = 0; t < 8; ++t) {
                const float4& x = v[h * 8 + t];
                c += (x.x > 0.f) + (x.y > 0.f) + (x.z > 0.f) + (x.w > 0.f);
            }
            int incl = c;
#pragma unroll
            for (int off = 1; off < 64; off <<= 1) {
                int y = __shfl_up(incl, off, 64);
                if (lane >= off) incl += y;
            }
            int p = base + incl - c;
            base += __shfl(incl, 63, 64);
#pragma unroll
            for (int t = 0; t < 8; ++t) {
                const float4& x = v[h * 8 + t];
                float f[4] = {x.x, x.y, x.z, x.w};
#pragma unroll
                for (int j = 0; j < 4; ++j)
                    if (f[j] > 0.f) {
                        if (p < CAP)
                            csr_c[wave * CAP + p] = (ushort_t)(((h * 8 + t) * 64 + lane) * 4 + j);
                        ++p;
                    }
            }
        }
        if (lane == 0) csr_n[wave] = (base < CAP) ? base : CAP;
    }
    __syncthreads();
    {
        const unsigned* cc = (const unsigned*)csr_c;
        if (tid < RPB * CAP / 2) gcols[b * (RPB * CAP / 2) + tid] = cc[tid];
        if (tid < RPB) cnt[r0 + tid] = csr_n[tid];
    }

    // ---- stage seq 16 x 512 (fp32 -> bf16, k-major frag layout)
    {
        int row = tid >> 6, seg = tid & 63;
        const float* p = seq + (size_t)(r0 + row) * 512 + seg * 8;
        float4 x0 = *(const float4*)p, x1 = *(const float4*)(p + 4);
        uint4 a;
        a.x = pack2(x0.x, x0.y); a.y = pack2(x0.z, x0.w);
        a.z = pack2(x1.x, x1.y); a.w = pack2(x1.z, x1.w);
        *(bf16x8*)(Astage + ((size_t)seg * 17 + row) * 8) = *(bf16x8*)&a;
    }
    __syncthreads();

    // ---- fc GEMM: wave -> 16 cols; epilogue -> fp8 x16 byte stores
    {
        const int col = wave * 16 + t16;
        const ushort_t* Wm = Wp + WP_FC;
        f32x4 a0 = {0.f, 0.f, 0.f, 0.f};
        for (int bch = 0; bch < 4; ++bch) {
            bf16x8 wb[4];
#pragma unroll
            for (int c2 = 0; c2 < 4; ++c2) {
                int k8c = (bch * 4 + c2) * 4 + kq;
                wb[c2] = *(const bf16x8*)(Wm + ((size_t)k8c * 256 + col) * 8);
            }
#pragma unroll
            for (int c2 = 0; c2 < 4; ++c2) {
                int c = bch * 4 + c2;
                bf16x8 af = *(const bf16x8*)(Astage + ((size_t)(c * 4 + kq) * 17 + t16) * 8);
                a0 = MFMA(af, wb[c2], a0);
            }
        }
#pragma unroll
        for (int r = 0; r < 4; ++r) {
            int t8 = __builtin_amdgcn_cvt_pk_fp8_f32(a0[r] * 16.f, 0.f, 0, false);
            regA8[(size_t)(r0 + kq * 4 + r) * OFT + col] = (u8)(t8 & 0xFF);
        }
    }
}

// ============== k2: spmm + q/k GEMM + norm + loss + h-GEMM ==================
__global__ __launch_bounds__(1024, 4) void k2_spmm_qk(
    const u8* __restrict__ regA8, unsigned* __restrict__ KO8,
    ushort_t* __restrict__ regH, const ushort_t* __restrict__ Wp,
    const unsigned* __restrict__ gcols, const int* __restrict__ cnt,
    float* __restrict__ part, float* __restrict__ invnk_g)
{
    __shared__ ushort_t Astage[32 * 17 * 8];
    __shared__ ushort_t csr_c[RPB * CAP];
    __shared__ ushort_t qn_l[RPB * QLS];
    __shared__ float    red[2][RPB][8];
    __shared__ float    dlred[16];

    const int tid = threadIdx.x, wave = tid >> 6, lane = tid & 63;
    const int t16 = lane & 15, kq = lane >> 4, grp = lane >> 4;
    const int b = blockIdx.x, r0 = b * RPB;
    const size_t batb = (size_t)(b >> 8) * 4096;

    {
        unsigned* cc = (unsigned*)csr_c;
        if (tid < RPB * CAP / 2) cc[tid] = gcols[b * (RPB * CAP / 2) + tid];
    }
    __syncthreads();

    // ---- spmm: wave -> row r0+wave
    {
        const int rl = wave;
        const int n = cnt[r0 + rl];
        const u8* gA = regA8 + batb * OFT;
        float a16[16];
#pragma unroll
        for (int j = 0; j < 16; ++j) a16[j] = 0.f;
        const int nIter = (n + 3) >> 2;
        uint4 v;
        {
            int e0 = grp; int val0 = (e0 < n);
            int col0 = csr_c[rl * CAP + (val0 ? e0 : 0)];
            v = *(const uint4*)(gA + (size_t)col0 * OFT + t16 * 16);
        }
        for (int it = 0; it < nIter; ++it) {
            uint4 vn;
            if (it + 1 < nIter) {
                int e1 = (it + 1) * 4 + grp; int val1 = (e1 < n);
                int col1 = csr_c[rl * CAP + (val1 ? e1 : 0)];
                vn = *(const uint4*)(gA + (size_t)col1 * OFT + t16 * 16);
            }
            int e = it * 4 + grp;
            if (e < n) {
                unsigned w4[4] = {v.x, v.y, v.z, v.w};
#pragma unroll
                for (int i2 = 0; i2 < 4; ++i2) {
                    f32x2 x01 = __builtin_amdgcn_cvt_pk_f32_fp8((int)w4[i2], false);
                    f32x2 x23 = __builtin_amdgcn_cvt_pk_f32_fp8((int)w4[i2], true);
                    a16[4*i2+0] += x01.x; a16[4*i2+1] += x01.y;
                    a16[4*i2+2] += x23.x; a16[4*i2+3] += x23.y;
                }
            }
            v = vn;
        }
#pragma unroll
        for (int j = 0; j < 16; ++j) {
            a16[j] += __shfl_xor(a16[j], 16, 64);
            a16[j] += __shfl_xor(a16[j], 32, 64);
        }
        float iv = 1.f / (16.f * (float)max(n, 1));
        float o0 = a16[grp*4+0]*iv, o1 = a16[grp*4+1]*iv;
        float o2 = a16[grp*4+2]*iv, o3 = a16[grp*4+3]*iv;
        int uo = 0;
        uo = __builtin_amdgcn_cvt_pk_fp8_f32(o0*16.f, o1*16.f, uo, false);
        uo = __builtin_amdgcn_cvt_pk_fp8_f32(o2*16.f, o3*16.f, uo, true);
        KO8[(size_t)(r0 + rl) * 64 + (t16 * 4 + grp)] = (unsigned)uo;
        int d0 = t16 * 16 + grp * 4;
        int q8c = d0 >> 3, off = d0 & 7;
        uint2 st; st.x = pack2(o0, o1); st.y = pack2(o2, o3);
        *(uint2*)(Astage + ((size_t)q8c * 17 + rl) * 8 + off) = st;
    }
    __syncthreads();

    // ---- q/k GEMM: waves 0-7 q, 8-15 k; wave -> 32 cols
    const int isK = wave >> 3, w8 = wave & 7;
    const ushort_t* Wm = Wp + (isK ? WP_K : WP_Q);
    f32x4 acc[2];
    acc[0] = (f32x4){0.f,0.f,0.f,0.f};
    acc[1] = (f32x4){0.f,0.f,0.f,0.f};
    for (int bch = 0; bch < 2; ++bch) {
        bf16x8 wb[2][4];
#pragma unroll
        for (int j = 0; j < 2; ++j)
#pragma unroll
            for (int c2 = 0; c2 < 4; ++c2) {
                int col = w8 * 32 + j * 16 + t16;
                int k8c = (bch * 4 + c2) * 4 + kq;
                wb[j][c2] = *(const bf16x8*)(Wm + ((size_t)k8c * 256 + col) * 8);
            }
#pragma unroll
        for (int c2 = 0; c2 < 4; ++c2) {
            int c = bch * 4 + c2;
            bf16x8 af = *(const bf16x8*)(Astage + ((size_t)(c*4 + kq) * 17 + t16) * 8);
            acc[0] = MFMA(af, wb[0][c2], acc[0]);
            acc[1] = MFMA(af, wb[1][c2], acc[1]);
        }
    }
#pragma unroll
    for (int r = 0; r < 4; ++r) {
        float s = acc[0][r]*acc[0][r] + acc[1][r]*acc[1][r];
#pragma unroll
        for (int off = 1; off < 16; off <<= 1) s += __shfl_xor(s, off, 16);
        if (t16 == 0) red[isK][kq*4 + r][w8] = s;
    }
    __syncthreads();
#pragma unroll
    for (int r = 0; r < 4; ++r) {
        int row = kq * 4 + r;
        float s = 0.f;
#pragma unroll
        for (int j = 0; j < 8; ++j) s += red[isK][row][j];
        float inv = 1.f / fmaxf(sqrtf(s), EPSN);
        if (isK && w8 == 0 && t16 == 0) invnk_g[r0 + row] = inv;
#pragma unroll
        for (int j = 0; j < 2; ++j) {
            int col = w8 * 32 + j * 16 + t16;
            float v = acc[j][r] * inv;
            acc[j][r] = v;
            if (!isK) qn_l[row * QLS + col] = f2bf(v);
        }
    }
    __syncthreads();
    if (isK) {
        float dl = 0.f;
#pragma unroll
        for (int r = 0; r < 4; ++r) {
            int row = kq * 4 + r;
#pragma unroll
            for (int j = 0; j < 2; ++j) {
                int col = w8 * 32 + j * 16 + t16;
                float d = bf2f(qn_l[row * QLS + col]) - acc[j][r];
                dl += d * d;
            }
        }
#pragma unroll
        for (int off = 1; off < 64; off <<= 1) dl += __shfl_xor(dl, off, 64);
        if (lane == 0) dlred[wave] = dl;
    }
    __syncthreads();

    // ---- h-GEMM: h[m] = qn[m] . Wk via WP_KT; 16 waves x 16 cols
    {
        const ushort_t* WmT = Wp + WP_KT;
        const int colh = wave * 16 + t16;
        f32x4 h0 = {0.f, 0.f, 0.f, 0.f};
        for (int bch = 0; bch < 2; ++bch) {
            bf16x8 wb[4];
#pragma unroll
            for (int c2 = 0; c2 < 4; ++c2) {
                int k8c = (bch * 4 + c2) * 4 + kq;
                wb[c2] = *(const bf16x8*)(WmT + ((size_t)k8c * 256 + colh) * 8);
            }
#pragma unroll
            for (int c2 = 0; c2 < 4; ++c2) {
                int k8c = (bch * 4 + c2) * 4 + kq;
                bf16x8 af = *(const bf16x8*)(qn_l + (size_t)t16 * QLS + k8c * 8);
                h0 = MFMA(af, wb[c2], h0);
            }
        }
#pragma unroll
        for (int r = 0; r < 4; ++r) {
            int row = kq * 4 + r;
            regH[(size_t)(r0 + row) * OFT + colh] = f2bf(h0[r]);
        }
    }
    if (tid == 0) {
        float s = 0.f;
#pragma unroll
        for (int j = 8; j < 16; ++j) s += dlred[j];
        part[b] = s;
    }
}

// ============== k3: fused attention + v1 + v2 (16 waves, 16 rows) ===========
__global__ __launch_bounds__(1024, 4) void k3_fused(
    const unsigned* __restrict__ KO8, const ushort_t* __restrict__ regH,
    const unsigned* __restrict__ gcols, const int* __restrict__ cnt,
    const ushort_t* __restrict__ Wp, const float* __restrict__ a_v,
    const float* __restrict__ a_act, const float* __restrict__ biasv,
    const float* __restrict__ part, const float* __restrict__ invnk_g,
    float* __restrict__ out)
{
    __shared__ ushort_t csr_c[RPB * CAP];
    __shared__ float    invl[RPB][CAP];
    __shared__ ushort_t Astage[32 * 17 * 8];   // ctx frag layout
    __shared__ ushort_t Hl[32 * 17 * 8];       // h frag layout
    __shared__ float    s8[16];

    const int tid = threadIdx.x, wave = tid >> 6, lane = tid & 63;
    const int t16 = lane & 15, kq = lane >> 4, grp = lane >> 4;
    const int b = blockIdx.x, r0 = b * RPB;
    const size_t batb = (size_t)(b >> 8) * 4096;

    if (b == 0 && tid < 512) {     // div_loss finalize
        float s = part[tid];
#pragma unroll
        for (int off = 32; off; off >>= 1) s += __shfl_down(s, off, 64);
        if (lane == 0) s8[wave] = s;
    }
    __syncthreads();
    if (b == 0 && tid == 0) {
        float t = 0.f;
#pragma unroll
        for (int j = 0; j < 8; ++j) t += s8[j];
        out[(size_t)ROWS * OFT] = t * (1.f / 8192.f);
    }

    {
        unsigned* cc = (unsigned*)csr_c;
        if (tid < RPB * CAP / 2) cc[tid] = gcols[b * (RPB * CAP / 2) + tid];
    }
    __syncthreads();

    // ---- attention: wave -> row; 4 edge slots; 2-deep prefetch
    {
        const int row = r0 + wave;
        const int n = cnt[row];
#pragma unroll
        for (int s = 0; s < 2; ++s) {
            int e = lane + s * 64;
            if (e < n) {
                int col = csr_c[wave * CAP + e];
                invl[wave][e] = invnk_g[batb + col] * 0.0625f;
            }
        }
        float q[16];
        {
            const ushort_t* qp = regH + (size_t)row * OFT + t16 * 16;
            uint4 a = *(const uint4*)qp, bq = *(const uint4*)(qp + 8);
            unsigned uu[8] = {a.x, a.y, a.z, a.w, bq.x, bq.y, bq.z, bq.w};
#pragma unroll
            for (int j = 0; j < 8; ++j) { q[2*j] = lo_f(uu[j]); q[2*j+1] = hi_f(uu[j]); }
        }
        const unsigned* gKO = KO8 + batb * 64;
        float c[16];
#pragma unroll
        for (int j = 0; j < 16; ++j) c[j] = 0.f;
        float sE = 0.f;
        const int nIter = (n + 3) >> 2;
        uint4 v0;
        {
            int e0 = grp; int val0 = (e0 < n);
            int col0 = csr_c[wave * CAP + (val0 ? e0 : 0)];
            v0 = *(const uint4*)(gKO + (size_t)col0 * 64 + t16 * 4);
        }
        for (int it = 0; it < nIter; ++it) {
            uint4 n0;
            if (it + 1 < nIter) {
                int e1 = (it + 1) * 4 + grp; int val1 = (e1 < n);
                int col1 = csr_c[wave * CAP + (val1 ? e1 : 0)];
                n0 = *(const uint4*)(gKO + (size_t)col1 * 64 + t16 * 4);
            }
            int e = it * 4 + grp;
            int valid = (e < n);
            float o[16];
            unsigned w4[4] = {v0.x, v0.y, v0.z, v0.w};
#pragma unroll
            for (int i2 = 0; i2 < 4; ++i2) {
                f32x2 x01 = __builtin_amdgcn_cvt_pk_f32_fp8((int)w4[i2], false);
                f32x2 x23 = __builtin_amdgcn_cvt_pk_f32_fp8((int)w4[i2], true);
                o[4*i2+0] = x01.x; o[4*i2+1] = x01.y;
                o[4*i2+2] = x23.x; o[4*i2+3] = x23.y;
            }
            float d = 0.f;
#pragma unroll
            for (int j = 0; j < 16; ++j) d += q[j] * o[j];
            d = dpp_add<0xB1>(d);    // quad xor1
            d = dpp_add<0x4E>(d);    // quad xor2
            d = dpp_add<0x124>(d);   // row_ror:4
            d = dpp_add<0x128>(d);   // row_ror:8
            float iv16v = invl[wave][valid ? e : 0];
            float es = __expf(d * iv16v);   // unscale outb x16 + k-norm
            es = valid ? es : 0.f;
            sE += es;
#pragma unroll
            for (int j = 0; j < 16; ++j) c[j] += es * o[j];
            v0 = n0;
        }
#pragma unroll
        for (int j = 0; j < 16; ++j) {
            c[j] += __shfl_xor(c[j], 16, 64);
            c[j] += __shfl_xor(c[j], 32, 64);
        }
        sE += __shfl_xor(sE, 16, 64);
        sE += __shfl_xor(sE, 32, 64);
        float inv16 = 0.0625f / sE;          // unscale outb x16 + softmax norm
        {
            int d0 = t16 * 16 + grp * 4;
            int q8c = d0 >> 3, off = d0 & 7;
            uint2 st; st.x = pack2(c[grp*4]*inv16, c[grp*4+1]*inv16);
            st.y = pack2(c[grp*4+2]*inv16, c[grp*4+3]*inv16);
            *(uint2*)(Astage + ((size_t)q8c * 17 + wave) * 8 + off) = st;
        }
    }
    __syncthreads();

    // ---- v1 GEMM + PReLU(a_v) -> Hl
    const int col = wave * 16 + t16;
    {
        const ushort_t* Wm = Wp + WP_V1;
        f32x4 h0 = {0.f,0.f,0.f,0.f};
        for (int bch = 0; bch < 2; ++bch) {
            bf16x8 wb[4];
#pragma unroll
            for (int c2 = 0; c2 < 4; ++c2) {
                int k8c = (bch * 4 + c2) * 4 + kq;
                wb[c2] = *(const bf16x8*)(Wm + ((size_t)k8c * 256 + col) * 8);
            }
#pragma unroll
            for (int c2 = 0; c2 < 4; ++c2) {
                int c = bch * 4 + c2;
                bf16x8 af = *(const bf16x8*)(Astage + ((size_t)(c*4 + kq) * 17 + t16) * 8);
                h0 = MFMA(af, wb[c2], h0);
            }
        }
        float av = *a_v;
        int q8c = col >> 3, off = col & 7;
#pragma unroll
        for (int r = 0; r < 4; ++r) {
            int row = kq * 4 + r;
            float x = h0[r]; x = (x >= 0.f) ? x : av * x;
            Hl[((size_t)q8c * 17 + row) * 8 + off] = f2bf(x);
        }
    }
    __syncthreads();

    // ---- v2 GEMM + bias + PReLU(a_act) -> out (fp32)
    {
        const ushort_t* Wm = Wp + WP_V2;
        f32x4 y0 = {0.f,0.f,0.f,0.f};
        for (int bch = 0; bch < 2; ++bch) {
            bf16x8 wb[4];
#pragma unroll
            for (int c2 = 0; c2 < 4; ++c2) {
                int k8c = (bch * 4 + c2) * 4 + kq;
                wb[c2] = *(const bf16x8*)(Wm + ((size_t)k8c * 256 + col) * 8);
            }
#pragma unroll
            for (int c2 = 0; c2 < 4; ++c2) {
                int c = bch * 4 + c2;
                bf16x8 af = *(const bf16x8*)(Hl + ((size_t)(c*4 + kq) * 17 + t16) * 8);
                y0 = MFMA(af, wb[c2], y0);
            }
        }
        float aa = *a_act;
        float bv = biasv[col];
#pragma unroll
        for (int r = 0; r < 4; ++r) {
            size_t row = (size_t)(r0 + kq * 4 + r);
            float x = y0[r] + bv; x = (x >= 0.f) ? x : aa * x;
            out[row * OFT + col] = x;
        }
    }
}

// ------------------------------------------------------------------- launch
extern "C" void kernel_launch(void* const* d_in, const int* in_sizes, int n_in,
                              void* d_out, int out_size, void* d_ws, size_t ws_size,
                              hipStream_t stream)
{
    const float* seq   = (const float*)d_in[0];
    const float* adj   = (const float*)d_in[1];
    const float* W_fc  = (const float*)d_in[2];
    const float* W_q   = (const float*)d_in[3];
    const float* W_k   = (const float*)d_in[4];
    const float* W_v1  = (const float*)d_in[5];
    const float* W_v2  = (const float*)d_in[6];
    const float* a_v   = (const float*)d_in[7];
    const float* a_act = (const float*)d_in[8];
    const float* bias  = (const float*)d_in[9];

    char* w = (char*)d_ws;
    u8*       regA8 = (u8*)w;                                // seq_fts fp8 2MB
    unsigned* KO8   = (unsigned*)(w + (4u  << 20));          // fp8 outb 2MB
    ushort_t* regH  = (ushort_t*)(w + (12u << 20));          // h=qn.Wk bf16 4MB
    unsigned* gcols = (unsigned*)(w + (16u << 20));          // CSR u16 cols 2MB
    int*      cnt   = (int*)(w + (20u << 20));               // 32KB
    float*    part  = (float*)(w + (20u << 20) + 32768);     // 2KB
    float*    invnk = (float*)(w + (20u << 20) + 65536);     // 32KB
    ushort_t* Wp    = (ushort_t*)(w + (21u << 20));          // 896KB frag weights

    k0_prep<<<224, 256, 0, stream>>>(W_fc, W_q, W_k, W_v1, W_v2, Wp);
    k1_extract_fc<<<NBLK, 1024, 0, stream>>>(seq, adj, Wp, regA8, gcols, cnt);
    k2_spmm_qk<<<NBLK, 1024, 0, stream>>>(regA8, KO8, regH, Wp, gcols, cnt,
                                          part, invnk);
    k3_fused<<<NBLK, 1024, 0, stream>>>(KO8, regH, gcols, cnt, Wp,
                                        a_v, a_act, bias, part, invnk,
                                        (float*)d_out);
}